// Round 15
// baseline (429.254 us; speedup 1.0000x reference)
//
#include <hip/hip_runtime.h>
#include <hip/hip_bf16.h>

#define D_ 128
#define H_ 8
#define N_ 20000
#define NNZ_ 500000
#define E_ 5000
#define C_ 50
#define NENT_ 50000
#define NK_ (3*N_)
#define CAPE_ 192
#define CAPN_ 64
#define ENT_PB 4096
#define NBKT 157
#define BCAP 3648
#define ABLK 123
#define NCH3 30             // chunks per head, 2048 keys each; 1 merged partial per chunk
#define KVBLK 235           // ceil(60000/256)

struct Ptr3f { const float* p[3]; };
struct Ptr3i { const int* p[3]; };
struct GemmB { const float* A[3]; const float* W[3]; unsigned short* C[3]; };

typedef short bf16x8 __attribute__((ext_vector_type(8)));
typedef float f32x4  __attribute__((ext_vector_type(4)));

__device__ __forceinline__ unsigned short f2b(float f){
  unsigned u = __float_as_uint(f);
  u += 0x7FFFu + ((u>>16)&1u);
  return (unsigned short)(u>>16);
}
__device__ __forceinline__ unsigned pk2(float a, float b){
  return (unsigned)f2b(a) | ((unsigned)f2b(b) << 16);
}
__device__ __forceinline__ float blo(unsigned u){ return __uint_as_float(u<<16); }
__device__ __forceinline__ float bhi(unsigned u){ return __uint_as_float(u & 0xFFFF0000u); }

// ---------------- prep: x2b + pack_bfB + zero gcnt + bfQ build + ctx-tail e2 rows ----------------
#define PB_PACK 7500
#define PB_Z    7628
#define PB_Q    7629
#define PB_CTX  7693
#define PB_TOT  7743
__global__ __launch_bounds__(256) void prep(Ptr3f xs, unsigned short* __restrict__ xb,
    const float* __restrict__ Wk, const float* __restrict__ Wv, unsigned short* __restrict__ bfB,
    int* __restrict__ gcnt_e, int* __restrict__ gcnt_n,
    const float* __restrict__ ctx, const float* __restrict__ Wq, const float* __restrict__ bq,
    unsigned short* __restrict__ bfQ,
    const float* __restrict__ a2, const float* __restrict__ b2, float* __restrict__ e2)
{
  int bid = blockIdx.x, t = threadIdx.x;
  if (bid < PB_PACK){
    int mod = bid / 2500, blk = bid - mod*2500;
    int i4 = blk*256 + t;
    float4 v = *(const float4*)(xs.p[mod] + (size_t)i4*4);
    ushort4 o; o.x=f2b(v.x); o.y=f2b(v.y); o.z=f2b(v.z); o.w=f2b(v.w);
    *(ushort4*)(xb + (size_t)mod*N_*D_ + (size_t)i4*4) = o;
  } else if (bid < PB_Z){
    int idx = (bid - PB_PACK)*256 + t;     // 32768
    int j  = idx & 7;
    int L  = (idx >> 3) & 63;
    int kb = (idx >> 9) & 3;
    int tt = idx >> 11;
    int k = kb*32 + (L>>4)*8 + j;
    int x = L & 15;
    float v = (tt < 8) ? Wk[(size_t)k*128 + tt*16 + x] : Wv[(size_t)k*128 + (tt-8)*16 + x];
    bfB[idx] = f2b(v);
  } else if (bid == PB_Z){
    for (int i=t; i<3*NBKT; i+=256){ gcnt_e[i]=0; gcnt_n[i]=0; }
  } else if (bid < PB_CTX){
    int idx = (bid - PB_Q)*256 + t;        // 16384
    int j  = idx & 7;
    int L  = (idx >> 3) & 63;
    int qt = (idx >> 9) & 3;
    int h  = idx >> 11;
    int k  = ((L>>4)&3)*8 + j;
    int q  = qt*16 + (L & 15);
    float val = 0.f;
    if (k < 16 && q < C_){
      const float* cr = ctx + (size_t)q*128;
      const float* wc = Wq + h*16 + k;
      float s0=0.f,s1=0.f,s2=0.f,s3=0.f;
      for (int d=0; d<128; d+=4){
        s0 = fmaf(cr[d],   wc[(size_t) d   *128], s0);
        s1 = fmaf(cr[d+1], wc[(size_t)(d+1)*128], s1);
        s2 = fmaf(cr[d+2], wc[(size_t)(d+2)*128], s2);
        s3 = fmaf(cr[d+3], wc[(size_t)(d+3)*128], s3);
      }
      val = 0.25f * (s0+s1+s2+s3 + bq[h*16+k]);
    }
    bfQ[idx] = f2b(val);
  } else {
    __shared__ float row[128];
    __shared__ float ps[128][2];
    __shared__ float red[2];
    int q = bid - PB_CTX;
    if (t < 128) row[t] = ctx[(size_t)q*128 + t];
    __syncthreads();
    int c = t & 127, half = t >> 7;
    float s = 0.f;
    int d0 = half*64;
    for (int d=d0; d<d0+64; d+=4){
      s = fmaf(row[d],   a2[(size_t) d   *128 + c], s);
      s = fmaf(row[d+1], a2[(size_t)(d+1)*128 + c], s);
      s = fmaf(row[d+2], a2[(size_t)(d+2)*128 + c], s);
      s = fmaf(row[d+3], a2[(size_t)(d+3)*128 + c], s);
    }
    ps[c][half] = s;
    __syncthreads();
    if (t < 128){
      float v = tanhf(ps[t][0] + ps[t][1]) * b2[t];
      #pragma unroll
      for (int k=32; k>=1; k>>=1) v += __shfl_xor(v, k);
      if ((t & 63) == 0) red[t>>6] = v;
    }
    __syncthreads();
    if (t == 0) e2[q] = red[0] + red[1];
  }
}

// ---------------- binA ----------------
__global__ __launch_bounds__(256) void binA(Ptr3i nodes, Ptr3i edges,
    unsigned* __restrict__ pe_part, unsigned* __restrict__ pn_part,
    int* __restrict__ gcnt_e, int* __restrict__ gcnt_n)
{
  __shared__ unsigned lbin[ENT_PB];
  __shared__ int cnt[256], off[256];
  __shared__ int gbase[NBKT];
  __shared__ int wsum[4];
  const int mod = blockIdx.y;
  const int* nd = nodes.p[mod];
  const int* ed = edges.p[mod];
  const int base = blockIdx.x * ENT_PB;
  const int t = threadIdx.x;
  const int lane = t & 63, w = t >> 6;

  int myn[16], mye[16], pos[16];
  #pragma unroll
  for (int k=0;k<16;k++){
    int i = base + t + k*256;
    if (i < NNZ_){ myn[k]=nd[i]; mye[k]=ed[i]; }
    else { myn[k]=-1; mye[k]=-1; }
  }

  cnt[t] = 0;
  __syncthreads();
  #pragma unroll
  for (int k=0;k<16;k++)
    if (mye[k] >= 0) pos[k] = atomicAdd(&cnt[mye[k]>>5], 1);
  __syncthreads();
  {
    int v = cnt[t], s = v;
    #pragma unroll
    for (int d=1; d<64; d<<=1){ int u=__shfl_up(s,d); if (lane>=d) s+=u; }
    if (lane==63) wsum[w]=s;
    __syncthreads();
    int wb=0;
    for (int i=0;i<w;i++) wb+=wsum[i];
    off[t] = wb + s - v;
    __syncthreads();
  }
  #pragma unroll
  for (int k=0;k<16;k++)
    if (mye[k] >= 0)
      lbin[off[mye[k]>>5] + pos[k]] = ((unsigned)mye[k] << 15) | (unsigned)myn[k];
  if (t < NBKT && cnt[t] > 0) gbase[t] = atomicAdd(&gcnt_e[mod*NBKT + t], cnt[t]);
  __syncthreads();
  {
    int total = off[255];
    unsigned* dstreg = pe_part + (size_t)mod*NBKT*BCAP;
    for (int i=t; i<total; i+=256){
      unsigned pk = lbin[i];
      int b = pk >> 20;
      int gp = gbase[b] + (i - off[b]);
      if (gp < BCAP) dstreg[(size_t)b*BCAP + gp] = pk;
    }
  }
  __syncthreads();

  cnt[t] = 0;
  __syncthreads();
  #pragma unroll
  for (int k=0;k<16;k++)
    if (myn[k] >= 0) pos[k] = atomicAdd(&cnt[myn[k]>>7], 1);
  __syncthreads();
  {
    int v = cnt[t], s = v;
    #pragma unroll
    for (int d=1; d<64; d<<=1){ int u=__shfl_up(s,d); if (lane>=d) s+=u; }
    if (lane==63) wsum[w]=s;
    __syncthreads();
    int wb=0;
    for (int i=0;i<w;i++) wb+=wsum[i];
    off[t] = wb + s - v;
    __syncthreads();
  }
  #pragma unroll
  for (int k=0;k<16;k++)
    if (myn[k] >= 0)
      lbin[off[myn[k]>>7] + pos[k]] = ((unsigned)myn[k] << 13) | (unsigned)mye[k];
  if (t < NBKT && cnt[t] > 0) gbase[t] = atomicAdd(&gcnt_n[mod*NBKT + t], cnt[t]);
  __syncthreads();
  {
    int total = off[255];
    unsigned* dstreg = pn_part + (size_t)mod*NBKT*BCAP;
    for (int i=t; i<total; i+=256){
      unsigned pk = lbin[i];
      int b = pk >> 20;
      int gp = gbase[b] + (i - off[b]);
      if (gp < BCAP) dstreg[(size_t)b*BCAP + gp] = pk;
    }
  }
}

// ---------------- fused binB_e + edge gather-mean ----------------
// grid (NBKT, 3): phase 1 builds 32-edge slot image in LDS; phase 2 gathers x rows.
__global__ __launch_bounds__(256) void binBe_gather(const unsigned* __restrict__ pe_part,
    const int* __restrict__ gcnt_e, const unsigned short* __restrict__ xb,
    float* __restrict__ m_mean)
{
  __shared__ unsigned short ls[32*CAPE_];   // 12 KB
  __shared__ int lc[32];
  const int mod = blockIdx.y, b = blockIdx.x, t = threadIdx.x;
  const int w = t >> 6, lane = t & 63;
  if (t < 32) lc[t] = 0;
  __syncthreads();
  int cnt = gcnt_e[mod*NBKT + b];
  if (cnt > BCAP) cnt = BCAP;
  const unsigned* src = pe_part + ((size_t)mod*NBKT + b)*BCAP;
  for (int i=t; i<cnt; i+=256){
    unsigned pk = src[i];
    int el = (pk >> 15) - b*32;
    int n  = pk & 0x7FFF;
    int p = atomicAdd(&lc[el], 1);
    if (p < CAPE_) ls[el*CAPE_ + p] = (unsigned short)n;
  }
  __syncthreads();

  const unsigned short* x = xb + (size_t)mod*N_*D_;
  for (int eo = 0; eo < 8; eo++){
    int el = w*8 + eo;
    int e = b*32 + el;
    if (e >= E_) break;
    int ec = lc[el];
    int c2 = (ec < CAPE_) ? ec : CAPE_;
    const unsigned short* slot = &ls[el*CAPE_];
    float a0=0.f,a1=0.f;
    int j = 0;
    for (; j+7 < c2; j += 8){
      unsigned uu[8];
      #pragma unroll
      for (int k=0;k<8;k++)
        uu[k] = *(const unsigned*)(x + (size_t)slot[j+k]*128 + lane*2);
      #pragma unroll
      for (int k=0;k<8;k++){ a0 += blo(uu[k]); a1 += bhi(uu[k]); }
    }
    for (; j < c2; j++){
      unsigned u0 = *(const unsigned*)(x + (size_t)slot[j]*128 + lane*2);
      a0 += blo(u0); a1 += bhi(u0);
    }
    float inv = 1.f / fmaxf((float)ec, 1.f);
    float2 o; o.x = a0*inv; o.y = a1*inv;
    *(float2*)(m_mean + ((size_t)mod*E_ + e)*128 + lane*2) = o;
  }
}

// ---------------- batched theta GEMM ----------------
__global__ __launch_bounds__(256) void gemm_b(GemmB g, int M)
{
  const float* A = g.A[blockIdx.y];
  const float* W = g.W[blockIdx.y];
  unsigned short* Cout = g.C[blockIdx.y];
  __shared__ float As[64][33];
  __shared__ float Ws[32][128];
  const int t  = threadIdx.x;
  const int br = blockIdx.x * 64;
  const int r0 = (t >> 5) * 8;
  const int c0 = (t & 31) * 4;
  const int lr = t >> 2;
  const int lk = (t & 3) * 8;
  const int wk = t >> 5;

  float acc[8][4];
  #pragma unroll
  for (int i=0;i<8;i++){ acc[i][0]=0.f; acc[i][1]=0.f; acc[i][2]=0.f; acc[i][3]=0.f; }

  for (int kb=0; kb<128; kb+=32){
    float av[8];
    const int grow = br + lr;
    if (grow < M){
      const float* p = A + (size_t)grow*128 + kb + lk;
      float4 a = ((const float4*)p)[0], b = ((const float4*)p)[1];
      av[0]=a.x;av[1]=a.y;av[2]=a.z;av[3]=a.w;av[4]=b.x;av[5]=b.y;av[6]=b.z;av[7]=b.w;
    } else {
      #pragma unroll
      for (int j=0;j<8;j++) av[j]=0.f;
    }
    float4 wv4[4];
    #pragma unroll
    for (int kk=0;kk<4;kk++) wv4[kk] = *(const float4*)&W[(size_t)(kb + wk + kk*8)*128 + c0];

    __syncthreads();
    #pragma unroll
    for (int j=0;j<8;j++) As[lr][lk+j] = av[j];
    #pragma unroll
    for (int kk=0;kk<4;kk++) *(float4*)&Ws[wk + kk*8][c0] = wv4[kk];
    __syncthreads();

    #pragma unroll
    for (int k=0;k<32;k++){
      float4 wv = *(const float4*)&Ws[k][c0];
      #pragma unroll
      for (int i=0;i<8;i++){
        float a = As[r0+i][k];
        acc[i][0] = fmaf(a, wv.x, acc[i][0]);
        acc[i][1] = fmaf(a, wv.y, acc[i][1]);
        acc[i][2] = fmaf(a, wv.z, acc[i][2]);
        acc[i][3] = fmaf(a, wv.w, acc[i][3]);
      }
    }
  }

  #pragma unroll
  for (int i=0;i<8;i++){
    int gr = br + r0 + i;
    if (gr < M){
      ushort4 o;
      o.x=f2b(acc[i][0]); o.y=f2b(acc[i][1]); o.z=f2b(acc[i][2]); o.w=f2b(acc[i][3]);
      *(ushort4*)(Cout + (size_t)gr*128 + c0) = o;
    }
  }
}

// ---------------- fused binB_n + node gather-mean + bias -> bf16 related ----------------
// grid (NBKT, 3): phase 1 builds 128-node slot image; phase 2 gathers m_buf rows.
__global__ __launch_bounds__(256) void binBn_gather(const unsigned* __restrict__ pn_part,
    const int* __restrict__ gcnt_n, const unsigned short* __restrict__ m_buf,
    Ptr3f biases, unsigned short* __restrict__ relbf)
{
  __shared__ unsigned short ls[128*CAPN_];   // 16 KB
  __shared__ int lc[128];
  const int mod = blockIdx.y, b = blockIdx.x, t = threadIdx.x;
  const int w = t >> 6, lane = t & 63;
  if (t < 128) lc[t] = 0;
  __syncthreads();
  int cnt = gcnt_n[mod*NBKT + b];
  if (cnt > BCAP) cnt = BCAP;
  const unsigned* src = pn_part + ((size_t)mod*NBKT + b)*BCAP;
  for (int i=t; i<cnt; i+=256){
    unsigned pk = src[i];
    int nl = (pk >> 13) - b*128;
    int e  = pk & 0x1FFF;
    int p = atomicAdd(&lc[nl], 1);
    if (p < CAPN_) ls[nl*CAPN_ + p] = (unsigned short)e;
  }
  __syncthreads();

  const unsigned short* m = m_buf + (size_t)mod*E_*D_;
  const float bias0 = biases.p[mod][lane*2];
  const float bias1 = biases.p[mod][lane*2+1];
  for (int no = 0; no < 32; no++){
    int nl = w*32 + no;
    int n = b*128 + nl;
    if (n >= N_) break;
    int ncnt = lc[nl];
    int c2 = (ncnt < CAPN_) ? ncnt : CAPN_;
    const unsigned short* slot = &ls[nl*CAPN_];
    float a0=0.f,a1=0.f;
    int j = 0;
    for (; j+7 < c2; j += 8){
      unsigned uu[8];
      #pragma unroll
      for (int k=0;k<8;k++)
        uu[k] = *(const unsigned*)(m + (size_t)slot[j+k]*128 + lane*2);
      #pragma unroll
      for (int k=0;k<8;k++){ a0 += blo(uu[k]); a1 += bhi(uu[k]); }
    }
    for (; j < c2; j++){
      unsigned u0 = *(const unsigned*)(m + (size_t)slot[j]*128 + lane*2);
      a0 += blo(u0); a1 += bhi(u0);
    }
    float inv = 1.f / fmaxf((float)ncnt, 1.f);
    float v0 = a0*inv + bias0;
    float v1 = a1*inv + bias1;
    unsigned out = (unsigned)f2b(v0) | ((unsigned)f2b(v1) << 16);
    *(unsigned*)(relbf + ((size_t)mod*N_ + n)*128 + lane*2) = out;
  }
}

// ---------------- MFMA KV GEMM: bfB staged in LDS, 256 rows/block ----------------
__global__ __launch_bounds__(256) void gemm_kv_mfma(const unsigned short* __restrict__ relbf,
    const unsigned short* __restrict__ bfB, const float* __restrict__ bk,
    const float* __restrict__ bv, unsigned short* __restrict__ Kb,
    unsigned short* __restrict__ Vtg)
{
  __shared__ unsigned short Bs[32768];   // all of bfB, 64 KB
  const int t = threadIdx.x, w = t >> 6, L = t & 63;
  const int m = L & 15, quad = L >> 4, x = m;

  {
    const uint4* src = (const uint4*)bfB;
    uint4* dst = (uint4*)Bs;
    for (int i = t; i < 4096; i += 256) dst[i] = src[i];
  }
  __syncthreads();

  const int rowbase = blockIdx.x*256;
  for (int g = 0; g < 4; g++){
    const int j0 = rowbase + g*64 + w*16;

    bf16x8 a[4];
    {
      int row = j0 + m;
      int rowc = (row < NK_) ? row : (NK_-1);
      #pragma unroll
      for (int kb=0; kb<4; kb++)
        a[kb] = *(const bf16x8*)(relbf + (size_t)rowc*128 + kb*32 + quad*8);
    }

    f32x4 acc[16];
    #pragma unroll
    for (int tt=0; tt<16; tt++) acc[tt] = (f32x4){0.f,0.f,0.f,0.f};

    #pragma unroll
    for (int kb=0; kb<4; kb++){
      #pragma unroll
      for (int tt=0; tt<16; tt++){
        bf16x8 b = *(const bf16x8*)&Bs[(((tt*4 + kb)*64 + L) << 3)];
        acc[tt] = __builtin_amdgcn_mfma_f32_16x16x32_bf16(a[kb], b, acc[tt], 0, 0, 0);
      }
    }

    #pragma unroll
    for (int tt=0; tt<16; tt++){
      int h = tt & 7, kv = tt >> 3;
      float bias = (kv ? bv : bk)[h*16 + x];
      #pragma unroll
      for (int r=0; r<4; r++){
        int jr = j0 + quad*4 + r;
        if (jr < NK_){
          unsigned short val = f2b(acc[tt][r] + bias);
          if (kv == 0) Kb[(((size_t)h*NK_ + jr) << 4) + x] = val;
          else         Vtg[((size_t)(h*16 + x))*NK_ + jr] = val;
        }
      }
    }
  }
}

// ---------------- MFMA flash with in-block 4-wave merge ----------------
__global__ __launch_bounds__(256) void flash3(const unsigned short* __restrict__ Kb,
    const unsigned short* __restrict__ Vtg, const unsigned short* __restrict__ bfQ,
    float* __restrict__ part)
{
  __shared__ unsigned short P_lds[4][64][40];
  __shared__ float mbuf[4][64][18];
  const int c = blockIdx.x, h = blockIdx.y;
  const int t = threadIdx.x, w = t >> 6, L = t & 63;
  const int n = L & 15, quad = L >> 4;

  bf16x8 qb[4];
  #pragma unroll
  for (int qt=0; qt<4; qt++)
    qb[qt] = *(const bf16x8*)(bfQ + (((h*4 + qt)*64 + L) << 3));

  float Mc[4], Lc[4];
  f32x4 accq[4];
  #pragma unroll
  for (int qt=0; qt<4; qt++){ Mc[qt] = -INFINITY; Lc[qt] = 0.f; accq[qt] = (f32x4){0.f,0.f,0.f,0.f}; }

  const int base = c*2048 + w*512;
  unsigned* Pw = (unsigned*)&P_lds[w][0][0];

  for (int tile=0; tile<16; tile++){
    const int j0 = base + tile*32;
    const bool dead = (j0 >= NK_);

    bf16x8 a0 = (bf16x8){0,0,0,0,0,0,0,0};
    bf16x8 a1 = a0;
    if (quad < 2){
      int k0 = j0 + n;      if (k0 > NK_-1) k0 = NK_-1;
      int k1 = j0 + 16 + n; if (k1 > NK_-1) k1 = NK_-1;
      a0 = *(const bf16x8*)(Kb + (((size_t)h*NK_ + k0) << 4) + quad*8);
      a1 = *(const bf16x8*)(Kb + (((size_t)h*NK_ + k1) << 4) + quad*8);
    }
    f32x4 s0[4], s1[4];
    #pragma unroll
    for (int qt=0; qt<4; qt++){
      s0[qt] = __builtin_amdgcn_mfma_f32_16x16x32_bf16(a0, qb[qt], (f32x4){0.f,0.f,0.f,0.f}, 0,0,0);
      s1[qt] = __builtin_amdgcn_mfma_f32_16x16x32_bf16(a1, qb[qt], (f32x4){0.f,0.f,0.f,0.f}, 0,0,0);
    }

    #pragma unroll
    for (int qt=0; qt<4; qt++){
      float mt = s0[qt][0];
      mt = fmaxf(mt, s0[qt][1]); mt = fmaxf(mt, s0[qt][2]); mt = fmaxf(mt, s0[qt][3]);
      mt = fmaxf(mt, s1[qt][0]); mt = fmaxf(mt, s1[qt][1]);
      mt = fmaxf(mt, s1[qt][2]); mt = fmaxf(mt, s1[qt][3]);
      mt = fmaxf(mt, __shfl_xor(mt, 16));
      mt = fmaxf(mt, __shfl_xor(mt, 32));
      float Mn = fmaxf(Mc[qt], mt);
      float corr = __expf(Mc[qt] - Mn);
      Mc[qt] = Mn;
      float p0[4], p1[4];
      #pragma unroll
      for (int r=0;r<4;r++){
        p0[r] = __expf(s0[qt][r] - Mn);
        p1[r] = __expf(s1[qt][r] - Mn);
      }
      if (dead){
        #pragma unroll
        for (int r=0;r<4;r++){ p0[r]=0.f; p1[r]=0.f; }
      }
      float lt = p0[0]+p0[1]+p0[2]+p0[3]+p1[0]+p1[1]+p1[2]+p1[3];
      lt += __shfl_xor(lt, 16);
      lt += __shfl_xor(lt, 32);
      Lc[qt] = Lc[qt]*corr + lt;
      int rb = (qt*16 + n)*20;
      Pw[rb + quad*2]     = pk2(p0[0], p0[1]);
      Pw[rb + quad*2 + 1] = pk2(p0[2], p0[3]);
      Pw[rb + 8 + quad*2]     = pk2(p1[0], p1[1]);
      Pw[rb + 8 + quad*2 + 1] = pk2(p1[2], p1[3]);
      #pragma unroll
      for (int r=0;r<4;r++){
        float cr = __shfl(corr, quad*4 + r);
        accq[qt][r] *= cr;
      }
    }
    __syncthreads();

    bf16x8 bv_;
    {
      int va = j0 + quad*8; if (va > NK_-8) va = NK_-8;
      bv_ = *(const bf16x8*)(Vtg + ((size_t)(h*16 + n))*NK_ + va);
    }
    #pragma unroll
    for (int qt=0; qt<4; qt++){
      bf16x8 pa = *(const bf16x8*)&P_lds[w][qt*16 + n][quad*8];
      accq[qt] = __builtin_amdgcn_mfma_f32_16x16x32_bf16(pa, bv_, accq[qt], 0,0,0);
    }
    __syncthreads();
  }

  #pragma unroll
  for (int qt=0; qt<4; qt++){
    #pragma unroll
    for (int r=0; r<4; r++)
      mbuf[w][qt*16 + quad*4 + r][2 + n] = accq[qt][r];
    if (quad == 0){
      mbuf[w][qt*16 + n][0] = Mc[qt];
      mbuf[w][qt*16 + n][1] = Lc[qt];
    }
  }
  __syncthreads();
  if (t < C_){
    float M = mbuf[0][t][0], Lm = mbuf[0][t][1];
    float A[16];
    #pragma unroll
    for (int i=0;i<16;i++) A[i] = mbuf[0][t][2+i];
    #pragma unroll
    for (int ww=1; ww<4; ww++){
      float pm = mbuf[ww][t][0], pl = mbuf[ww][t][1];
      if (pl > 0.f){
        float mn = fmaxf(M, pm);
        float c1 = __expf(M - mn), c2 = __expf(pm - mn);
        Lm = Lm*c1 + pl*c2;
        #pragma unroll
        for (int i=0;i<16;i++) A[i] = A[i]*c1 + mbuf[ww][t][2+i]*c2;
        M = mn;
      }
    }
    float* pp = part + ((size_t)(h*NCH3 + c)*C_ + t)*18;
    pp[0] = M; pp[1] = Lm;
    #pragma unroll
    for (int i=0;i<16;i++) pp[2+i] = A[i];
  }
}

// ---------------- fused flash-reduce (two-pass, ILP) + O-projection + e1 row ----------------
__global__ __launch_bounds__(128) void reduce_oproj_e1(const float* __restrict__ part,
    const float* __restrict__ Wo, const float* __restrict__ bo,
    const float* __restrict__ a1, const float* __restrict__ b1,
    float* __restrict__ attentive, float* __restrict__ e1)
{
  __shared__ float row[128];
  __shared__ float orow[128];
  __shared__ float red[2];
  const int q = blockIdx.x, t = threadIdx.x;
  const int h = t >> 4, x = t & 15;
  const float* pbase = part + ((size_t)h*NCH3*C_ + q)*18;

  float M = -INFINITY;
  #pragma unroll 5
  for (int c=0; c<NCH3; c++){
    const float* p = pbase + (size_t)c*C_*18;
    float pm = p[0], pl = p[1];
    M = fmaxf(M, (pl > 0.f) ? pm : -INFINITY);
  }
  float l = 0.f, a = 0.f;
  #pragma unroll 5
  for (int c=0; c<NCH3; c++){
    const float* p = pbase + (size_t)c*C_*18;
    float pm = p[0], pl = p[1];
    float wgt = (pl > 0.f) ? __expf(pm - M) : 0.f;
    l = fmaf(pl, wgt, l);
    a = fmaf(p[2+x], wgt, a);
  }
  row[t] = a / l;
  __syncthreads();
  float s0=0.f,s1=0.f,s2=0.f,s3=0.f;
  for (int d=0; d<128; d+=4){
    s0 = fmaf(row[d],   Wo[(size_t) d   *128 + t], s0);
    s1 = fmaf(row[d+1], Wo[(size_t)(d+1)*128 + t], s1);
    s2 = fmaf(row[d+2], Wo[(size_t)(d+2)*128 + t], s2);
    s3 = fmaf(row[d+3], Wo[(size_t)(d+3)*128 + t], s3);
  }
  float o = s0+s1+s2+s3 + bo[t];
  attentive[(size_t)q*128 + t] = o;
  orow[t] = o;
  __syncthreads();
  float e0=0.f,e1s=0.f,e2s=0.f,e3s=0.f;
  for (int d=0; d<128; d+=4){
    e0 = fmaf(orow[d],   a1[(size_t) d   *128 + t], e0);
    e1s= fmaf(orow[d+1], a1[(size_t)(d+1)*128 + t], e1s);
    e2s= fmaf(orow[d+2], a1[(size_t)(d+2)*128 + t], e2s);
    e3s= fmaf(orow[d+3], a1[(size_t)(d+3)*128 + t], e3s);
  }
  float v = tanhf(e0+e1s+e2s+e3s) * b1[t];
  #pragma unroll
  for (int k=32; k>=1; k>>=1) v += __shfl_xor(v, k);
  if ((t & 63) == 0) red[t>>6] = v;
  __syncthreads();
  if (t == 0) e1[q] = red[0] + red[1];
}

// ---------------- tail_mid ----------------
__global__ __launch_bounds__(128) void tail_mid(const float* __restrict__ attentive,
    const float* __restrict__ ctx, const float* __restrict__ a2, const float* __restrict__ b2,
    const float* __restrict__ e1, const float* __restrict__ e2, float* __restrict__ user_repr)
{
  __shared__ float p[64];
  __shared__ float u[128];
  __shared__ float red[2];
  __shared__ float p2[64];
  const int t = threadIdx.x;

  if (t == 0){
    float mx=-INFINITY;
    for (int i=0;i<C_;i++) mx=fmaxf(mx,e1[i]);
    float ss=0.f;
    for (int i=0;i<C_;i++){ p[i]=__expf(e1[i]-mx); ss+=p[i]; }
    float inv=1.f/ss;
    for (int i=0;i<C_;i++) p[i]*=inv;
  }
  __syncthreads();
  {
    float s=0.f;
    for (int r=0;r<C_;r++) s = fmaf(p[r], attentive[(size_t)r*128 + t], s);
    u[t] = s;
  }
  __syncthreads();
  {
    float s0=0.f,s1=0.f,s2=0.f,s3=0.f;
    for (int d=0; d<128; d+=4){
      s0 = fmaf(u[d],   a2[(size_t) d   *128 + t], s0);
      s1 = fmaf(u[d+1], a2[(size_t)(d+1)*128 + t], s1);
      s2 = fmaf(u[d+2], a2[(size_t)(d+2)*128 + t], s2);
      s3 = fmaf(u[d+3], a2[(size_t)(d+3)*128 + t], s3);
    }
    float v = tanhf(s0+s1+s2+s3) * b2[t];
    #pragma unroll
    for (int k=32; k>=1; k>>=1) v += __shfl_xor(v, k);
    if ((t & 63) == 0) red[t>>6] = v;
  }
  __syncthreads();
  if (t == 0){
    float elast = red[0] + red[1];
    float mx=elast;
    for (int i=0;i<C_;i++) mx=fmaxf(mx,e2[i]);
    float ss=0.f;
    for (int i=0;i<C_;i++){ p2[i]=__expf(e2[i]-mx); ss+=p2[i]; }
    float pl = __expf(elast-mx); ss += pl;
    float inv=1.f/ss;
    for (int i=0;i<C_;i++) p2[i]*=inv;
    p2[C_] = pl*inv;
  }
  __syncthreads();
  {
    float s=0.f;
    for (int r=0;r<C_;r++) s = fmaf(p2[r], ctx[(size_t)r*128 + t], s);
    s = fmaf(p2[C_], u[t], s);
    user_repr[t] = s;
  }
}

__global__ __launch_bounds__(256) void scores_k(const float* __restrict__ ur,
    const float* __restrict__ recW, const float* __restrict__ recb, float* __restrict__ out)
{
  __shared__ float u[128];
  int t = threadIdx.x;
  if (t < 128) u[t] = ur[t];
  __syncthreads();
  int j = blockIdx.x*256 + t;
  if (j < NENT_){
    float s0=0.f,s1=0.f,s2=0.f,s3=0.f;
    for (int d=0; d<128; d+=4){
      s0 = fmaf(u[d],   recW[(size_t) d   *NENT_ + j], s0);
      s1 = fmaf(u[d+1], recW[(size_t)(d+1)*NENT_ + j], s1);
      s2 = fmaf(u[d+2], recW[(size_t)(d+2)*NENT_ + j], s2);
      s3 = fmaf(u[d+3], recW[(size_t)(d+3)*NENT_ + j], s3);
    }
    out[j] = s0+s1+s2+s3 + recb[j];
  }
}

// ---------------- launcher ----------------
extern "C" void kernel_launch(void* const* d_in, const int* in_sizes, int n_in,
                              void* d_out, int out_size, void* d_ws, size_t ws_size,
                              hipStream_t stream)
{
  auto f32 = [&](int i){ return (const float*)d_in[i]; };
  Ptr3i nodes = {{(const int*)d_in[24], (const int*)d_in[26], (const int*)d_in[28]}};
  Ptr3i edges = {{(const int*)d_in[25], (const int*)d_in[27], (const int*)d_in[29]}};

  // ---- workspace layout (~70 MB) ----
  char* base = (char*)d_ws;
  int*   gcnt_e  = (int*)base;                                    // 471
  int*   gcnt_n  = gcnt_e + NBKT*3;                               // 471
  float* m_mean  = (float*)(base + 4096);                         // 3*E*D f
  unsigned short* m_buf = (unsigned short*)((char*)m_mean + 7680000);   // 3*E*D ush
  unsigned short* relbf = (unsigned short*)((char*)m_buf + 3840000);    // 3*N*D ush
  unsigned short* bfB   = (unsigned short*)((char*)relbf + 15360000);   // 32,768 ush
  unsigned short* bfQ   = (unsigned short*)((char*)bfB + 65536);        // 16,384 ush
  float* attentive = (float*)((char*)bfQ + 32768);
  float* user_repr = (float*)((char*)attentive + 25600);
  float* e1buf     = user_repr + 128;
  float* e2buf     = e1buf + 64;
  float* fpart = (float*)relbf;   // overlays relbf (dead after gemm_kv_mfma)
  char* U = (char*)(e2buf + 64);
  unsigned* pe_part = (unsigned*)U;                               // 3*NBKT*BCAP u32 = 6.87 MB
  unsigned* pn_part = pe_part + (size_t)3*NBKT*BCAP;              // 6.87 MB
  unsigned short* xb = (unsigned short*)(pn_part + (size_t)3*NBKT*BCAP); // 15.36 MB
  // Kb+Vtg (30.72 MB) overlay U; U region = 6.87+6.87+15.36 = 29.1 MB -> pad ensures fit
  unsigned short* Kb  = (unsigned short*)U;
  unsigned short* Vtg = Kb + (size_t)H_*NK_*16;
  // (U sized implicitly; total ws usage ~70 MB incl. 30.72 MB overlay max)

  // ---- prep (+ctx-tail e2 rows) ----
  Ptr3f xs = {{f32(0), f32(1), f32(2)}};
  prep<<<PB_TOT, 256, 0, stream>>>(xs, xb, f32(12), f32(14), bfB, gcnt_e, gcnt_n,
                                   f32(3), f32(10), f32(11), bfQ, f32(20), f32(21), e2buf);

  // ---- binned CSR build + fused gathers ----
  binA<<<dim3(ABLK, 3), 256, 0, stream>>>(nodes, edges, pe_part, pn_part, gcnt_e, gcnt_n);
  binBe_gather<<<dim3(NBKT, 3), 256, 0, stream>>>(pe_part, gcnt_e, xb, m_mean);
  GemmB g;
  for (int mod=0; mod<3; mod++){
    g.A[mod] = m_mean + (size_t)mod*E_*D_;
    g.W[mod] = f32(4 + 2*mod);
    g.C[mod] = m_buf + (size_t)mod*E_*D_;
  }
  gemm_b<<<dim3((E_+63)/64, 3), 256, 0, stream>>>(g, E_);
  Ptr3f biases = {{f32(5), f32(7), f32(9)}};
  binBn_gather<<<dim3(NBKT, 3), 256, 0, stream>>>(pn_part, gcnt_n, m_buf, biases, relbf);

  // ---- MHA ----
  gemm_kv_mfma<<<KVBLK, 256, 0, stream>>>(relbf, bfB, f32(13), f32(15), Kb, Vtg);
  flash3<<<dim3(NCH3, H_), 256, 0, stream>>>(Kb, Vtg, bfQ, fpart);
  reduce_oproj_e1<<<C_, 128, 0, stream>>>(fpart, f32(16), f32(17), f32(18), f32(19),
                                          attentive, e1buf);

  // ---- tail ----
  tail_mid<<<1, 128, 0, stream>>>(attentive, f32(3), f32(20), f32(21), e1buf, e2buf, user_repr);
  scores_k<<<(NENT_+255)/256, 256, 0, stream>>>(user_repr, f32(22), f32(23), (float*)d_out);
}

// Round 16
// 395.976 us; speedup vs baseline: 1.0840x; 1.0840x over previous
//
#include <hip/hip_runtime.h>
#include <hip/hip_bf16.h>

#define D_ 128
#define H_ 8
#define N_ 20000
#define NNZ_ 500000
#define E_ 5000
#define C_ 50
#define NENT_ 50000
#define NK_ (3*N_)
#define CAPE_ 192
#define CAPN_ 64
#define ENT_PB 4096
#define NBKT 157
#define BCAP 3648
#define ABLK 123
#define NCH3 30             // chunks per head, 2048 keys each; 1 merged partial per chunk
#define KVBLK 235           // ceil(60000/256)

struct Ptr3f { const float* p[3]; };
struct Ptr3i { const int* p[3]; };
struct GemmB { const float* A[3]; const float* W[3]; unsigned short* C[3]; };

typedef short bf16x8 __attribute__((ext_vector_type(8)));
typedef float f32x4  __attribute__((ext_vector_type(4)));

__device__ __forceinline__ unsigned short f2b(float f){
  unsigned u = __float_as_uint(f);
  u += 0x7FFFu + ((u>>16)&1u);
  return (unsigned short)(u>>16);
}
__device__ __forceinline__ unsigned pk2(float a, float b){
  return (unsigned)f2b(a) | ((unsigned)f2b(b) << 16);
}
__device__ __forceinline__ float blo(unsigned u){ return __uint_as_float(u<<16); }
__device__ __forceinline__ float bhi(unsigned u){ return __uint_as_float(u & 0xFFFF0000u); }

// ---------------- prep: x2b + pack_bfB + zero gcnt + bfQ build + ctx-tail e2 rows ----------------
#define PB_PACK 7500
#define PB_Z    7628
#define PB_Q    7629
#define PB_CTX  7693
#define PB_TOT  7743
__global__ __launch_bounds__(256) void prep(Ptr3f xs, unsigned short* __restrict__ xb,
    const float* __restrict__ Wk, const float* __restrict__ Wv, unsigned short* __restrict__ bfB,
    int* __restrict__ gcnt_e, int* __restrict__ gcnt_n,
    const float* __restrict__ ctx, const float* __restrict__ Wq, const float* __restrict__ bq,
    unsigned short* __restrict__ bfQ,
    const float* __restrict__ a2, const float* __restrict__ b2, float* __restrict__ e2)
{
  int bid = blockIdx.x, t = threadIdx.x;
  if (bid < PB_PACK){
    int mod = bid / 2500, blk = bid - mod*2500;
    int i4 = blk*256 + t;
    float4 v = *(const float4*)(xs.p[mod] + (size_t)i4*4);
    ushort4 o; o.x=f2b(v.x); o.y=f2b(v.y); o.z=f2b(v.z); o.w=f2b(v.w);
    *(ushort4*)(xb + (size_t)mod*N_*D_ + (size_t)i4*4) = o;
  } else if (bid < PB_Z){
    int idx = (bid - PB_PACK)*256 + t;     // 32768
    int j  = idx & 7;
    int L  = (idx >> 3) & 63;
    int kb = (idx >> 9) & 3;
    int tt = idx >> 11;
    int k = kb*32 + (L>>4)*8 + j;
    int x = L & 15;
    float v = (tt < 8) ? Wk[(size_t)k*128 + tt*16 + x] : Wv[(size_t)k*128 + (tt-8)*16 + x];
    bfB[idx] = f2b(v);
  } else if (bid == PB_Z){
    for (int i=t; i<3*NBKT; i+=256){ gcnt_e[i]=0; gcnt_n[i]=0; }
  } else if (bid < PB_CTX){
    int idx = (bid - PB_Q)*256 + t;        // 16384
    int j  = idx & 7;
    int L  = (idx >> 3) & 63;
    int qt = (idx >> 9) & 3;
    int h  = idx >> 11;
    int k  = ((L>>4)&3)*8 + j;
    int q  = qt*16 + (L & 15);
    float val = 0.f;
    if (k < 16 && q < C_){
      const float* cr = ctx + (size_t)q*128;
      const float* wc = Wq + h*16 + k;
      float s0=0.f,s1=0.f,s2=0.f,s3=0.f;
      for (int d=0; d<128; d+=4){
        s0 = fmaf(cr[d],   wc[(size_t) d   *128], s0);
        s1 = fmaf(cr[d+1], wc[(size_t)(d+1)*128], s1);
        s2 = fmaf(cr[d+2], wc[(size_t)(d+2)*128], s2);
        s3 = fmaf(cr[d+3], wc[(size_t)(d+3)*128], s3);
      }
      val = 0.25f * (s0+s1+s2+s3 + bq[h*16+k]);
    }
    bfQ[idx] = f2b(val);
  } else {
    __shared__ float row[128];
    __shared__ float ps[128][2];
    __shared__ float red[2];
    int q = bid - PB_CTX;
    if (t < 128) row[t] = ctx[(size_t)q*128 + t];
    __syncthreads();
    int c = t & 127, half = t >> 7;
    float s = 0.f;
    int d0 = half*64;
    for (int d=d0; d<d0+64; d+=4){
      s = fmaf(row[d],   a2[(size_t) d   *128 + c], s);
      s = fmaf(row[d+1], a2[(size_t)(d+1)*128 + c], s);
      s = fmaf(row[d+2], a2[(size_t)(d+2)*128 + c], s);
      s = fmaf(row[d+3], a2[(size_t)(d+3)*128 + c], s);
    }
    ps[c][half] = s;
    __syncthreads();
    if (t < 128){
      float v = tanhf(ps[t][0] + ps[t][1]) * b2[t];
      #pragma unroll
      for (int k=32; k>=1; k>>=1) v += __shfl_xor(v, k);
      if ((t & 63) == 0) red[t>>6] = v;
    }
    __syncthreads();
    if (t == 0) e2[q] = red[0] + red[1];
  }
}

// ---------------- binA ----------------
__global__ __launch_bounds__(256) void binA(Ptr3i nodes, Ptr3i edges,
    unsigned* __restrict__ pe_part, unsigned* __restrict__ pn_part,
    int* __restrict__ gcnt_e, int* __restrict__ gcnt_n)
{
  __shared__ unsigned lbin[ENT_PB];
  __shared__ int cnt[256], off[256];
  __shared__ int gbase[NBKT];
  __shared__ int wsum[4];
  const int mod = blockIdx.y;
  const int* nd = nodes.p[mod];
  const int* ed = edges.p[mod];
  const int base = blockIdx.x * ENT_PB;
  const int t = threadIdx.x;
  const int lane = t & 63, w = t >> 6;

  int myn[16], mye[16], pos[16];
  #pragma unroll
  for (int k=0;k<16;k++){
    int i = base + t + k*256;
    if (i < NNZ_){ myn[k]=nd[i]; mye[k]=ed[i]; }
    else { myn[k]=-1; mye[k]=-1; }
  }

  cnt[t] = 0;
  __syncthreads();
  #pragma unroll
  for (int k=0;k<16;k++)
    if (mye[k] >= 0) pos[k] = atomicAdd(&cnt[mye[k]>>5], 1);
  __syncthreads();
  {
    int v = cnt[t], s = v;
    #pragma unroll
    for (int d=1; d<64; d<<=1){ int u=__shfl_up(s,d); if (lane>=d) s+=u; }
    if (lane==63) wsum[w]=s;
    __syncthreads();
    int wb=0;
    for (int i=0;i<w;i++) wb+=wsum[i];
    off[t] = wb + s - v;
    __syncthreads();
  }
  #pragma unroll
  for (int k=0;k<16;k++)
    if (mye[k] >= 0)
      lbin[off[mye[k]>>5] + pos[k]] = ((unsigned)mye[k] << 15) | (unsigned)myn[k];
  if (t < NBKT && cnt[t] > 0) gbase[t] = atomicAdd(&gcnt_e[mod*NBKT + t], cnt[t]);
  __syncthreads();
  {
    int total = off[255];
    unsigned* dstreg = pe_part + (size_t)mod*NBKT*BCAP;
    for (int i=t; i<total; i+=256){
      unsigned pk = lbin[i];
      int b = pk >> 20;
      int gp = gbase[b] + (i - off[b]);
      if (gp < BCAP) dstreg[(size_t)b*BCAP + gp] = pk;
    }
  }
  __syncthreads();

  cnt[t] = 0;
  __syncthreads();
  #pragma unroll
  for (int k=0;k<16;k++)
    if (myn[k] >= 0) pos[k] = atomicAdd(&cnt[myn[k]>>7], 1);
  __syncthreads();
  {
    int v = cnt[t], s = v;
    #pragma unroll
    for (int d=1; d<64; d<<=1){ int u=__shfl_up(s,d); if (lane>=d) s+=u; }
    if (lane==63) wsum[w]=s;
    __syncthreads();
    int wb=0;
    for (int i=0;i<w;i++) wb+=wsum[i];
    off[t] = wb + s - v;
    __syncthreads();
  }
  #pragma unroll
  for (int k=0;k<16;k++)
    if (myn[k] >= 0)
      lbin[off[myn[k]>>7] + pos[k]] = ((unsigned)myn[k] << 13) | (unsigned)mye[k];
  if (t < NBKT && cnt[t] > 0) gbase[t] = atomicAdd(&gcnt_n[mod*NBKT + t], cnt[t]);
  __syncthreads();
  {
    int total = off[255];
    unsigned* dstreg = pn_part + (size_t)mod*NBKT*BCAP;
    for (int i=t; i<total; i+=256){
      unsigned pk = lbin[i];
      int b = pk >> 20;
      int gp = gbase[b] + (i - off[b]);
      if (gp < BCAP) dstreg[(size_t)b*BCAP + gp] = pk;
    }
  }
}

// ---------------- binB (merged e+n) ----------------
__global__ __launch_bounds__(256) void binB(const unsigned* __restrict__ pe_part,
    const unsigned* __restrict__ pn_part,
    const int* __restrict__ gcnt_e, const int* __restrict__ gcnt_n,
    int* __restrict__ cnt_all,
    unsigned short* __restrict__ e_slot, unsigned short* __restrict__ n_slot)
{
  __shared__ unsigned short ls[128*CAPN_];
  __shared__ int lc[128];
  const int y = blockIdx.y, b = blockIdx.x, t = threadIdx.x;
  if (y < 3){
    const int mod = y;
    if (t < 32) lc[t] = 0;
    __syncthreads();
    int cnt = gcnt_e[mod*NBKT + b];
    if (cnt > BCAP) cnt = BCAP;
    const unsigned* src = pe_part + ((size_t)mod*NBKT + b)*BCAP;
    for (int i=t; i<cnt; i+=256){
      unsigned pk = src[i];
      int el = (pk >> 15) - b*32;
      int n  = pk & 0x7FFF;
      int p = atomicAdd(&lc[el], 1);
      if (p < CAPE_) ls[el*CAPE_ + p] = (unsigned short)n;
    }
    __syncthreads();
    int rows = E_ - b*32; if (rows > 32) rows = 32;
    if (t < rows) cnt_all[mod*(E_+N_) + b*32 + t] = lc[t];
    const unsigned* lsu = (const unsigned*)ls;
    unsigned* dst = (unsigned*)(e_slot + ((size_t)mod*E_ + b*32)*CAPE_);
    int tot = rows*CAPE_/2;
    for (int i=t; i<tot; i+=256) dst[i] = lsu[i];
  } else {
    const int mod = y - 3;
    if (t < 128) lc[t] = 0;
    __syncthreads();
    int cnt = gcnt_n[mod*NBKT + b];
    if (cnt > BCAP) cnt = BCAP;
    const unsigned* src = pn_part + ((size_t)mod*NBKT + b)*BCAP;
    for (int i=t; i<cnt; i+=256){
      unsigned pk = src[i];
      int nl = (pk >> 13) - b*128;
      int e  = pk & 0x1FFF;
      int p = atomicAdd(&lc[nl], 1);
      if (p < CAPN_) ls[nl*CAPN_ + p] = (unsigned short)e;
    }
    __syncthreads();
    int rows = N_ - b*128; if (rows > 128) rows = 128;
    if (t < rows) cnt_all[mod*(E_+N_) + E_ + b*128 + t] = lc[t];
    const unsigned* lsu = (const unsigned*)ls;
    unsigned* dst = (unsigned*)(n_slot + ((size_t)mod*N_ + b*128)*CAPN_);
    int tot = rows*CAPN_/2;
    for (int i=t; i<tot; i+=256) dst[i] = lsu[i];
  }
}

// ---------------- wave-per-edge gather-mean (8-deep ILP) ----------------
__global__ __launch_bounds__(256) void e_gather_w(const unsigned short* __restrict__ xb,
    const int* __restrict__ cnt_all, const unsigned short* __restrict__ e_slot,
    float* __restrict__ m_mean)
{
  int mod = blockIdx.y;
  int w = threadIdx.x >> 6, lane = threadIdx.x & 63;
  int e = blockIdx.x*4 + w;
  const unsigned short* x = xb + (size_t)mod*N_*D_;
  int cnt = cnt_all[mod*(E_+N_) + e];
  int c2 = (cnt < CAPE_) ? cnt : CAPE_;
  const unsigned short* slot = e_slot + ((size_t)mod*E_ + e)*CAPE_;
  float a0=0.f,a1=0.f;
  int j=0;
  for (; j+7 < c2; j += 8){
    unsigned uu[8];
    #pragma unroll
    for (int k=0;k<8;k++)
      uu[k] = *(const unsigned*)(x + (size_t)slot[j+k]*128 + lane*2);
    #pragma unroll
    for (int k=0;k<8;k++){ a0 += blo(uu[k]); a1 += bhi(uu[k]); }
  }
  for (; j < c2; j++){
    unsigned u0 = *(const unsigned*)(x + (size_t)slot[j]*128 + lane*2);
    a0 += blo(u0); a1 += bhi(u0);
  }
  float inv = 1.f / fmaxf((float)cnt, 1.f);
  float2 o; o.x = a0*inv; o.y = a1*inv;
  *(float2*)(m_mean + ((size_t)mod*E_ + e)*128 + lane*2) = o;
}

// ---------------- batched theta GEMM ----------------
__global__ __launch_bounds__(256) void gemm_b(GemmB g, int M)
{
  const float* A = g.A[blockIdx.y];
  const float* W = g.W[blockIdx.y];
  unsigned short* Cout = g.C[blockIdx.y];
  __shared__ float As[64][33];
  __shared__ float Ws[32][128];
  const int t  = threadIdx.x;
  const int br = blockIdx.x * 64;
  const int r0 = (t >> 5) * 8;
  const int c0 = (t & 31) * 4;
  const int lr = t >> 2;
  const int lk = (t & 3) * 8;
  const int wk = t >> 5;

  float acc[8][4];
  #pragma unroll
  for (int i=0;i<8;i++){ acc[i][0]=0.f; acc[i][1]=0.f; acc[i][2]=0.f; acc[i][3]=0.f; }

  for (int kb=0; kb<128; kb+=32){
    float av[8];
    const int grow = br + lr;
    if (grow < M){
      const float* p = A + (size_t)grow*128 + kb + lk;
      float4 a = ((const float4*)p)[0], b = ((const float4*)p)[1];
      av[0]=a.x;av[1]=a.y;av[2]=a.z;av[3]=a.w;av[4]=b.x;av[5]=b.y;av[6]=b.z;av[7]=b.w;
    } else {
      #pragma unroll
      for (int j=0;j<8;j++) av[j]=0.f;
    }
    float4 wv4[4];
    #pragma unroll
    for (int kk=0;kk<4;kk++) wv4[kk] = *(const float4*)&W[(size_t)(kb + wk + kk*8)*128 + c0];

    __syncthreads();
    #pragma unroll
    for (int j=0;j<8;j++) As[lr][lk+j] = av[j];
    #pragma unroll
    for (int kk=0;kk<4;kk++) *(float4*)&Ws[wk + kk*8][c0] = wv4[kk];
    __syncthreads();

    #pragma unroll
    for (int k=0;k<32;k++){
      float4 wv = *(const float4*)&Ws[k][c0];
      #pragma unroll
      for (int i=0;i<8;i++){
        float a = As[r0+i][k];
        acc[i][0] = fmaf(a, wv.x, acc[i][0]);
        acc[i][1] = fmaf(a, wv.y, acc[i][1]);
        acc[i][2] = fmaf(a, wv.z, acc[i][2]);
        acc[i][3] = fmaf(a, wv.w, acc[i][3]);
      }
    }
  }

  #pragma unroll
  for (int i=0;i<8;i++){
    int gr = br + r0 + i;
    if (gr < M){
      ushort4 o;
      o.x=f2b(acc[i][0]); o.y=f2b(acc[i][1]); o.z=f2b(acc[i][2]); o.w=f2b(acc[i][3]);
      *(ushort4*)(Cout + (size_t)gr*128 + c0) = o;
    }
  }
}

// ---------------- wave-per-node gather-mean + bias -> bf16 related (8-deep ILP) ----------------
__global__ __launch_bounds__(256) void n_gather_w(const unsigned short* __restrict__ m_buf,
    const int* __restrict__ cnt_all, const unsigned short* __restrict__ n_slot,
    Ptr3f biases, unsigned short* __restrict__ relbf)
{
  int mod = blockIdx.y;
  int w = threadIdx.x >> 6, lane = threadIdx.x & 63;
  int n = blockIdx.x*4 + w;
  const unsigned short* m = m_buf + (size_t)mod*E_*D_;
  int cnt = cnt_all[mod*(E_+N_) + E_ + n];
  int c2 = (cnt < CAPN_) ? cnt : CAPN_;
  const unsigned short* slot = n_slot + ((size_t)mod*N_ + n)*CAPN_;
  float a0=0.f,a1=0.f;
  int j=0;
  for (; j+7 < c2; j += 8){
    unsigned uu[8];
    #pragma unroll
    for (int k=0;k<8;k++)
      uu[k] = *(const unsigned*)(m + (size_t)slot[j+k]*128 + lane*2);
    #pragma unroll
    for (int k=0;k<8;k++){ a0 += blo(uu[k]); a1 += bhi(uu[k]); }
  }
  for (; j < c2; j++){
    unsigned u0 = *(const unsigned*)(m + (size_t)slot[j]*128 + lane*2);
    a0 += blo(u0); a1 += bhi(u0);
  }
  float inv = 1.f / fmaxf((float)cnt, 1.f);
  float v0 = a0*inv + biases.p[mod][lane*2];
  float v1 = a1*inv + biases.p[mod][lane*2+1];
  unsigned out = (unsigned)f2b(v0) | ((unsigned)f2b(v1) << 16);
  *(unsigned*)(relbf + ((size_t)mod*N_ + n)*128 + lane*2) = out;
}

// ---------------- MFMA KV GEMM: bfB staged in LDS, 256 rows/block ----------------
__global__ __launch_bounds__(256) void gemm_kv_mfma(const unsigned short* __restrict__ relbf,
    const unsigned short* __restrict__ bfB, const float* __restrict__ bk,
    const float* __restrict__ bv, unsigned short* __restrict__ Kb,
    unsigned short* __restrict__ Vtg)
{
  __shared__ unsigned short Bs[32768];   // all of bfB, 64 KB
  const int t = threadIdx.x, w = t >> 6, L = t & 63;
  const int m = L & 15, quad = L >> 4, x = m;

  {
    const uint4* src = (const uint4*)bfB;
    uint4* dst = (uint4*)Bs;
    for (int i = t; i < 4096; i += 256) dst[i] = src[i];
  }
  __syncthreads();

  const int rowbase = blockIdx.x*256;
  for (int g = 0; g < 4; g++){
    const int j0 = rowbase + g*64 + w*16;

    bf16x8 a[4];
    {
      int row = j0 + m;
      int rowc = (row < NK_) ? row : (NK_-1);
      #pragma unroll
      for (int kb=0; kb<4; kb++)
        a[kb] = *(const bf16x8*)(relbf + (size_t)rowc*128 + kb*32 + quad*8);
    }

    f32x4 acc[16];
    #pragma unroll
    for (int tt=0; tt<16; tt++) acc[tt] = (f32x4){0.f,0.f,0.f,0.f};

    #pragma unroll
    for (int kb=0; kb<4; kb++){
      #pragma unroll
      for (int tt=0; tt<16; tt++){
        bf16x8 b = *(const bf16x8*)&Bs[(((tt*4 + kb)*64 + L) << 3)];
        acc[tt] = __builtin_amdgcn_mfma_f32_16x16x32_bf16(a[kb], b, acc[tt], 0, 0, 0);
      }
    }

    #pragma unroll
    for (int tt=0; tt<16; tt++){
      int h = tt & 7, kv = tt >> 3;
      float bias = (kv ? bv : bk)[h*16 + x];
      #pragma unroll
      for (int r=0; r<4; r++){
        int jr = j0 + quad*4 + r;
        if (jr < NK_){
          unsigned short val = f2b(acc[tt][r] + bias);
          if (kv == 0) Kb[(((size_t)h*NK_ + jr) << 4) + x] = val;
          else         Vtg[((size_t)(h*16 + x))*NK_ + jr] = val;
        }
      }
    }
  }
}

// ---------------- MFMA flash with in-block 4-wave merge ----------------
__global__ __launch_bounds__(256) void flash3(const unsigned short* __restrict__ Kb,
    const unsigned short* __restrict__ Vtg, const unsigned short* __restrict__ bfQ,
    float* __restrict__ part)
{
  __shared__ unsigned short P_lds[4][64][40];
  __shared__ float mbuf[4][64][18];
  const int c = blockIdx.x, h = blockIdx.y;
  const int t = threadIdx.x, w = t >> 6, L = t & 63;
  const int n = L & 15, quad = L >> 4;

  bf16x8 qb[4];
  #pragma unroll
  for (int qt=0; qt<4; qt++)
    qb[qt] = *(const bf16x8*)(bfQ + (((h*4 + qt)*64 + L) << 3));

  float Mc[4], Lc[4];
  f32x4 accq[4];
  #pragma unroll
  for (int qt=0; qt<4; qt++){ Mc[qt] = -INFINITY; Lc[qt] = 0.f; accq[qt] = (f32x4){0.f,0.f,0.f,0.f}; }

  const int base = c*2048 + w*512;
  unsigned* Pw = (unsigned*)&P_lds[w][0][0];

  for (int tile=0; tile<16; tile++){
    const int j0 = base + tile*32;
    const bool dead = (j0 >= NK_);

    bf16x8 a0 = (bf16x8){0,0,0,0,0,0,0,0};
    bf16x8 a1 = a0;
    if (quad < 2){
      int k0 = j0 + n;      if (k0 > NK_-1) k0 = NK_-1;
      int k1 = j0 + 16 + n; if (k1 > NK_-1) k1 = NK_-1;
      a0 = *(const bf16x8*)(Kb + (((size_t)h*NK_ + k0) << 4) + quad*8);
      a1 = *(const bf16x8*)(Kb + (((size_t)h*NK_ + k1) << 4) + quad*8);
    }
    f32x4 s0[4], s1[4];
    #pragma unroll
    for (int qt=0; qt<4; qt++){
      s0[qt] = __builtin_amdgcn_mfma_f32_16x16x32_bf16(a0, qb[qt], (f32x4){0.f,0.f,0.f,0.f}, 0,0,0);
      s1[qt] = __builtin_amdgcn_mfma_f32_16x16x32_bf16(a1, qb[qt], (f32x4){0.f,0.f,0.f,0.f}, 0,0,0);
    }

    #pragma unroll
    for (int qt=0; qt<4; qt++){
      float mt = s0[qt][0];
      mt = fmaxf(mt, s0[qt][1]); mt = fmaxf(mt, s0[qt][2]); mt = fmaxf(mt, s0[qt][3]);
      mt = fmaxf(mt, s1[qt][0]); mt = fmaxf(mt, s1[qt][1]);
      mt = fmaxf(mt, s1[qt][2]); mt = fmaxf(mt, s1[qt][3]);
      mt = fmaxf(mt, __shfl_xor(mt, 16));
      mt = fmaxf(mt, __shfl_xor(mt, 32));
      float Mn = fmaxf(Mc[qt], mt);
      float corr = __expf(Mc[qt] - Mn);
      Mc[qt] = Mn;
      float p0[4], p1[4];
      #pragma unroll
      for (int r=0;r<4;r++){
        p0[r] = __expf(s0[qt][r] - Mn);
        p1[r] = __expf(s1[qt][r] - Mn);
      }
      if (dead){
        #pragma unroll
        for (int r=0;r<4;r++){ p0[r]=0.f; p1[r]=0.f; }
      }
      float lt = p0[0]+p0[1]+p0[2]+p0[3]+p1[0]+p1[1]+p1[2]+p1[3];
      lt += __shfl_xor(lt, 16);
      lt += __shfl_xor(lt, 32);
      Lc[qt] = Lc[qt]*corr + lt;
      int rb = (qt*16 + n)*20;
      Pw[rb + quad*2]     = pk2(p0[0], p0[1]);
      Pw[rb + quad*2 + 1] = pk2(p0[2], p0[3]);
      Pw[rb + 8 + quad*2]     = pk2(p1[0], p1[1]);
      Pw[rb + 8 + quad*2 + 1] = pk2(p1[2], p1[3]);
      #pragma unroll
      for (int r=0;r<4;r++){
        float cr = __shfl(corr, quad*4 + r);
        accq[qt][r] *= cr;
      }
    }
    __syncthreads();

    bf16x8 bv_;
    {
      int va = j0 + quad*8; if (va > NK_-8) va = NK_-8;
      bv_ = *(const bf16x8*)(Vtg + ((size_t)(h*16 + n))*NK_ + va);
    }
    #pragma unroll
    for (int qt=0; qt<4; qt++){
      bf16x8 pa = *(const bf16x8*)&P_lds[w][qt*16 + n][quad*8];
      accq[qt] = __builtin_amdgcn_mfma_f32_16x16x32_bf16(pa, bv_, accq[qt], 0,0,0);
    }
    __syncthreads();
  }

  #pragma unroll
  for (int qt=0; qt<4; qt++){
    #pragma unroll
    for (int r=0; r<4; r++)
      mbuf[w][qt*16 + quad*4 + r][2 + n] = accq[qt][r];
    if (quad == 0){
      mbuf[w][qt*16 + n][0] = Mc[qt];
      mbuf[w][qt*16 + n][1] = Lc[qt];
    }
  }
  __syncthreads();
  if (t < C_){
    float M = mbuf[0][t][0], Lm = mbuf[0][t][1];
    float A[16];
    #pragma unroll
    for (int i=0;i<16;i++) A[i] = mbuf[0][t][2+i];
    #pragma unroll
    for (int ww=1; ww<4; ww++){
      float pm = mbuf[ww][t][0], pl = mbuf[ww][t][1];
      if (pl > 0.f){
        float mn = fmaxf(M, pm);
        float c1 = __expf(M - mn), c2 = __expf(pm - mn);
        Lm = Lm*c1 + pl*c2;
        #pragma unroll
        for (int i=0;i<16;i++) A[i] = A[i]*c1 + mbuf[ww][t][2+i]*c2;
        M = mn;
      }
    }
    float* pp = part + ((size_t)(h*NCH3 + c)*C_ + t)*18;
    pp[0] = M; pp[1] = Lm;
    #pragma unroll
    for (int i=0;i<16;i++) pp[2+i] = A[i];
  }
}

// ---------------- fused flash-reduce (two-pass, ILP) + O-projection + e1 row ----------------
__global__ __launch_bounds__(128) void reduce_oproj_e1(const float* __restrict__ part,
    const float* __restrict__ Wo, const float* __restrict__ bo,
    const float* __restrict__ a1, const float* __restrict__ b1,
    float* __restrict__ attentive, float* __restrict__ e1)
{
  __shared__ float row[128];
  __shared__ float orow[128];
  __shared__ float red[2];
  const int q = blockIdx.x, t = threadIdx.x;
  const int h = t >> 4, x = t & 15;
  const float* pbase = part + ((size_t)h*NCH3*C_ + q)*18;

  float M = -INFINITY;
  #pragma unroll 5
  for (int c=0; c<NCH3; c++){
    const float* p = pbase + (size_t)c*C_*18;
    float pm = p[0], pl = p[1];
    M = fmaxf(M, (pl > 0.f) ? pm : -INFINITY);
  }
  float l = 0.f, a = 0.f;
  #pragma unroll 5
  for (int c=0; c<NCH3; c++){
    const float* p = pbase + (size_t)c*C_*18;
    float pm = p[0], pl = p[1];
    float wgt = (pl > 0.f) ? __expf(pm - M) : 0.f;
    l = fmaf(pl, wgt, l);
    a = fmaf(p[2+x], wgt, a);
  }
  row[t] = a / l;
  __syncthreads();
  float s0=0.f,s1=0.f,s2=0.f,s3=0.f;
  for (int d=0; d<128; d+=4){
    s0 = fmaf(row[d],   Wo[(size_t) d   *128 + t], s0);
    s1 = fmaf(row[d+1], Wo[(size_t)(d+1)*128 + t], s1);
    s2 = fmaf(row[d+2], Wo[(size_t)(d+2)*128 + t], s2);
    s3 = fmaf(row[d+3], Wo[(size_t)(d+3)*128 + t], s3);
  }
  float o = s0+s1+s2+s3 + bo[t];
  attentive[(size_t)q*128 + t] = o;
  orow[t] = o;
  __syncthreads();
  float e0=0.f,e1s=0.f,e2s=0.f,e3s=0.f;
  for (int d=0; d<128; d+=4){
    e0 = fmaf(orow[d],   a1[(size_t) d   *128 + t], e0);
    e1s= fmaf(orow[d+1], a1[(size_t)(d+1)*128 + t], e1s);
    e2s= fmaf(orow[d+2], a1[(size_t)(d+2)*128 + t], e2s);
    e3s= fmaf(orow[d+3], a1[(size_t)(d+3)*128 + t], e3s);
  }
  float v = tanhf(e0+e1s+e2s+e3s) * b1[t];
  #pragma unroll
  for (int k=32; k>=1; k>>=1) v += __shfl_xor(v, k);
  if ((t & 63) == 0) red[t>>6] = v;
  __syncthreads();
  if (t == 0) e1[q] = red[0] + red[1];
}

// ---------------- tail_mid ----------------
__global__ __launch_bounds__(128) void tail_mid(const float* __restrict__ attentive,
    const float* __restrict__ ctx, const float* __restrict__ a2, const float* __restrict__ b2,
    const float* __restrict__ e1, const float* __restrict__ e2, float* __restrict__ user_repr)
{
  __shared__ float p[64];
  __shared__ float u[128];
  __shared__ float red[2];
  __shared__ float p2[64];
  const int t = threadIdx.x;

  if (t == 0){
    float mx=-INFINITY;
    for (int i=0;i<C_;i++) mx=fmaxf(mx,e1[i]);
    float ss=0.f;
    for (int i=0;i<C_;i++){ p[i]=__expf(e1[i]-mx); ss+=p[i]; }
    float inv=1.f/ss;
    for (int i=0;i<C_;i++) p[i]*=inv;
  }
  __syncthreads();
  {
    float s=0.f;
    for (int r=0;r<C_;r++) s = fmaf(p[r], attentive[(size_t)r*128 + t], s);
    u[t] = s;
  }
  __syncthreads();
  {
    float s0=0.f,s1=0.f,s2=0.f,s3=0.f;
    for (int d=0; d<128; d+=4){
      s0 = fmaf(u[d],   a2[(size_t) d   *128 + t], s0);
      s1 = fmaf(u[d+1], a2[(size_t)(d+1)*128 + t], s1);
      s2 = fmaf(u[d+2], a2[(size_t)(d+2)*128 + t], s2);
      s3 = fmaf(u[d+3], a2[(size_t)(d+3)*128 + t], s3);
    }
    float v = tanhf(s0+s1+s2+s3) * b2[t];
    #pragma unroll
    for (int k=32; k>=1; k>>=1) v += __shfl_xor(v, k);
    if ((t & 63) == 0) red[t>>6] = v;
  }
  __syncthreads();
  if (t == 0){
    float elast = red[0] + red[1];
    float mx=elast;
    for (int i=0;i<C_;i++) mx=fmaxf(mx,e2[i]);
    float ss=0.f;
    for (int i=0;i<C_;i++){ p2[i]=__expf(e2[i]-mx); ss+=p2[i]; }
    float pl = __expf(elast-mx); ss += pl;
    float inv=1.f/ss;
    for (int i=0;i<C_;i++) p2[i]*=inv;
    p2[C_] = pl*inv;
  }
  __syncthreads();
  {
    float s=0.f;
    for (int r=0;r<C_;r++) s = fmaf(p2[r], ctx[(size_t)r*128 + t], s);
    s = fmaf(p2[C_], u[t], s);
    user_repr[t] = s;
  }
}

__global__ __launch_bounds__(256) void scores_k(const float* __restrict__ ur,
    const float* __restrict__ recW, const float* __restrict__ recb, float* __restrict__ out)
{
  __shared__ float u[128];
  int t = threadIdx.x;
  if (t < 128) u[t] = ur[t];
  __syncthreads();
  int j = blockIdx.x*256 + t;
  if (j < NENT_){
    float s0=0.f,s1=0.f,s2=0.f,s3=0.f;
    for (int d=0; d<128; d+=4){
      s0 = fmaf(u[d],   recW[(size_t) d   *NENT_ + j], s0);
      s1 = fmaf(u[d+1], recW[(size_t)(d+1)*NENT_ + j], s1);
      s2 = fmaf(u[d+2], recW[(size_t)(d+2)*NENT_ + j], s2);
      s3 = fmaf(u[d+3], recW[(size_t)(d+3)*NENT_ + j], s3);
    }
    out[j] = s0+s1+s2+s3 + recb[j];
  }
}

// ---------------- launcher ----------------
extern "C" void kernel_launch(void* const* d_in, const int* in_sizes, int n_in,
                              void* d_out, int out_size, void* d_ws, size_t ws_size,
                              hipStream_t stream)
{
  auto f32 = [&](int i){ return (const float*)d_in[i]; };
  Ptr3i nodes = {{(const int*)d_in[24], (const int*)d_in[26], (const int*)d_in[28]}};
  Ptr3i edges = {{(const int*)d_in[25], (const int*)d_in[27], (const int*)d_in[29]}};

  // ---- workspace layout (~75 MB) ----
  char* base = (char*)d_ws;
  int*   cnt_all = (int*)base;
  int*   gcnt_e  = (int*)(base + 300064);
  int*   gcnt_n  = gcnt_e + NBKT*3;
  unsigned short* n_slot = (unsigned short*)(base + 300064 + 4096);
  float* m_mean  = (float*)((char*)n_slot + 7680000);
  unsigned short* m_buf = (unsigned short*)((char*)m_mean + 7680000);
  unsigned short* relbf = (unsigned short*)((char*)m_buf + 3840000);
  unsigned short* bfB   = (unsigned short*)((char*)relbf + 15360000);
  unsigned short* bfQ   = (unsigned short*)((char*)bfB + 65536);
  float* attentive = (float*)((char*)bfQ + 32768);
  float* user_repr = (float*)((char*)attentive + 25600);
  float* e1buf     = user_repr + 128;
  float* e2buf     = e1buf + 64;
  float* fpart = (float*)relbf;   // overlays relbf (dead after gemm_kv_mfma)
  char* U = (char*)(e2buf + 64);
  unsigned* pe_part = (unsigned*)U;
  unsigned* pn_part = pe_part + (size_t)3*NBKT*BCAP;
  unsigned short* e_slot = (unsigned short*)(pn_part + (size_t)3*NBKT*BCAP);
  unsigned short* xb     = e_slot + (size_t)3*E_*CAPE_;
  unsigned short* Kb  = (unsigned short*)U;
  unsigned short* Vtg = Kb + (size_t)H_*NK_*16;

  // ---- prep (+ctx-tail e2 rows) ----
  Ptr3f xs = {{f32(0), f32(1), f32(2)}};
  prep<<<PB_TOT, 256, 0, stream>>>(xs, xb, f32(12), f32(14), bfB, gcnt_e, gcnt_n,
                                   f32(3), f32(10), f32(11), bfQ, f32(20), f32(21), e2buf);

  // ---- binned CSR build ----
  binA<<<dim3(ABLK, 3), 256, 0, stream>>>(nodes, edges, pe_part, pn_part, gcnt_e, gcnt_n);
  binB<<<dim3(NBKT, 6), 256, 0, stream>>>(pe_part, pn_part, gcnt_e, gcnt_n, cnt_all,
                                          e_slot, n_slot);

  // ---- hyperconv gathers + theta GEMM ----
  e_gather_w<<<dim3(E_/4, 3), 256, 0, stream>>>(xb, cnt_all, e_slot, m_mean);
  GemmB g;
  for (int mod=0; mod<3; mod++){
    g.A[mod] = m_mean + (size_t)mod*E_*D_;
    g.W[mod] = f32(4 + 2*mod);
    g.C[mod] = m_buf + (size_t)mod*E_*D_;
  }
  gemm_b<<<dim3((E_+63)/64, 3), 256, 0, stream>>>(g, E_);
  Ptr3f biases = {{f32(5), f32(7), f32(9)}};
  n_gather_w<<<dim3(N_/4, 3), 256, 0, stream>>>(m_buf, cnt_all, n_slot, biases, relbf);

  // ---- MHA ----
  gemm_kv_mfma<<<KVBLK, 256, 0, stream>>>(relbf, bfB, f32(13), f32(15), Kb, Vtg);
  flash3<<<dim3(NCH3, H_), 256, 0, stream>>>(Kb, Vtg, bfQ, fpart);
  reduce_oproj_e1<<<C_, 128, 0, stream>>>(fpart, f32(16), f32(17), f32(18), f32(19),
                                          attentive, e1buf);

  // ---- tail ----
  tail_mid<<<1, 128, 0, stream>>>(attentive, f32(3), f32(20), f32(21), e1buf, e2buf, user_repr);
  scores_k<<<(NENT_+255)/256, 256, 0, stream>>>(user_repr, f32(22), f32(23), (float*)d_out);
}

// Round 17
// 394.797 us; speedup vs baseline: 1.0873x; 1.0030x over previous
//
#include <hip/hip_runtime.h>
#include <hip/hip_bf16.h>

#define D_ 128
#define H_ 8
#define N_ 20000
#define NNZ_ 500000
#define E_ 5000
#define C_ 50
#define NENT_ 50000
#define NK_ (3*N_)
#define CAPE_ 192
#define CAPN_ 64
#define ENT_PB 4096
#define NBKT 157
#define BCAP 3648
#define ABLK 123
#define NCH3 30             // chunks per head, 2048 keys each; 1 merged partial per chunk
#define KVBLK 235           // ceil(60000/256)

struct Ptr3f { const float* p[3]; };
struct Ptr3i { const int* p[3]; };
struct GemmB { const float* A[3]; const float* W[3]; unsigned short* C[3]; };

typedef short bf16x8 __attribute__((ext_vector_type(8)));
typedef float f32x4  __attribute__((ext_vector_type(4)));

__device__ __forceinline__ unsigned short f2b(float f){
  unsigned u = __float_as_uint(f);
  u += 0x7FFFu + ((u>>16)&1u);
  return (unsigned short)(u>>16);
}
__device__ __forceinline__ unsigned pk2(float a, float b){
  return (unsigned)f2b(a) | ((unsigned)f2b(b) << 16);
}
__device__ __forceinline__ float blo(unsigned u){ return __uint_as_float(u<<16); }
__device__ __forceinline__ float bhi(unsigned u){ return __uint_as_float(u & 0xFFFF0000u); }

// ---------------- prep: x2b + pack_bfB + zero gcnt + bfQ build + ctx-tail e2 rows ----------------
#define PB_PACK 7500
#define PB_Z    7628
#define PB_Q    7629
#define PB_CTX  7693
#define PB_TOT  7743
__global__ __launch_bounds__(256) void prep(Ptr3f xs, unsigned short* __restrict__ xb,
    const float* __restrict__ Wk, const float* __restrict__ Wv, unsigned short* __restrict__ bfB,
    int* __restrict__ gcnt_e, int* __restrict__ gcnt_n,
    const float* __restrict__ ctx, const float* __restrict__ Wq, const float* __restrict__ bq,
    unsigned short* __restrict__ bfQ,
    const float* __restrict__ a2, const float* __restrict__ b2, float* __restrict__ e2)
{
  int bid = blockIdx.x, t = threadIdx.x;
  if (bid < PB_PACK){
    int mod = bid / 2500, blk = bid - mod*2500;
    int i4 = blk*256 + t;
    float4 v = *(const float4*)(xs.p[mod] + (size_t)i4*4);
    ushort4 o; o.x=f2b(v.x); o.y=f2b(v.y); o.z=f2b(v.z); o.w=f2b(v.w);
    *(ushort4*)(xb + (size_t)mod*N_*D_ + (size_t)i4*4) = o;
  } else if (bid < PB_Z){
    int idx = (bid - PB_PACK)*256 + t;     // 32768
    int j  = idx & 7;
    int L  = (idx >> 3) & 63;
    int kb = (idx >> 9) & 3;
    int tt = idx >> 11;
    int k = kb*32 + (L>>4)*8 + j;
    int x = L & 15;
    float v = (tt < 8) ? Wk[(size_t)k*128 + tt*16 + x] : Wv[(size_t)k*128 + (tt-8)*16 + x];
    bfB[idx] = f2b(v);
  } else if (bid == PB_Z){
    for (int i=t; i<3*NBKT; i+=256){ gcnt_e[i]=0; gcnt_n[i]=0; }
  } else if (bid < PB_CTX){
    int idx = (bid - PB_Q)*256 + t;        // 16384
    int j  = idx & 7;
    int L  = (idx >> 3) & 63;
    int qt = (idx >> 9) & 3;
    int h  = idx >> 11;
    int k  = ((L>>4)&3)*8 + j;
    int q  = qt*16 + (L & 15);
    float val = 0.f;
    if (k < 16 && q < C_){
      const float* cr = ctx + (size_t)q*128;
      const float* wc = Wq + h*16 + k;
      float s0=0.f,s1=0.f,s2=0.f,s3=0.f;
      for (int d=0; d<128; d+=4){
        s0 = fmaf(cr[d],   wc[(size_t) d   *128], s0);
        s1 = fmaf(cr[d+1], wc[(size_t)(d+1)*128], s1);
        s2 = fmaf(cr[d+2], wc[(size_t)(d+2)*128], s2);
        s3 = fmaf(cr[d+3], wc[(size_t)(d+3)*128], s3);
      }
      val = 0.25f * (s0+s1+s2+s3 + bq[h*16+k]);
    }
    bfQ[idx] = f2b(val);
  } else {
    __shared__ float row[128];
    __shared__ float ps[128][2];
    __shared__ float red[2];
    int q = bid - PB_CTX;
    if (t < 128) row[t] = ctx[(size_t)q*128 + t];
    __syncthreads();
    int c = t & 127, half = t >> 7;
    float s = 0.f;
    int d0 = half*64;
    for (int d=d0; d<d0+64; d+=4){
      s = fmaf(row[d],   a2[(size_t) d   *128 + c], s);
      s = fmaf(row[d+1], a2[(size_t)(d+1)*128 + c], s);
      s = fmaf(row[d+2], a2[(size_t)(d+2)*128 + c], s);
      s = fmaf(row[d+3], a2[(size_t)(d+3)*128 + c], s);
    }
    ps[c][half] = s;
    __syncthreads();
    if (t < 128){
      float v = tanhf(ps[t][0] + ps[t][1]) * b2[t];
      #pragma unroll
      for (int k=32; k>=1; k>>=1) v += __shfl_xor(v, k);
      if ((t & 63) == 0) red[t>>6] = v;
    }
    __syncthreads();
    if (t == 0) e2[q] = red[0] + red[1];
  }
}

// ---------------- binA ----------------
__global__ __launch_bounds__(256) void binA(Ptr3i nodes, Ptr3i edges,
    unsigned* __restrict__ pe_part, unsigned* __restrict__ pn_part,
    int* __restrict__ gcnt_e, int* __restrict__ gcnt_n)
{
  __shared__ unsigned lbin[ENT_PB];
  __shared__ int cnt[256], off[256];
  __shared__ int gbase[NBKT];
  __shared__ int wsum[4];
  const int mod = blockIdx.y;
  const int* nd = nodes.p[mod];
  const int* ed = edges.p[mod];
  const int base = blockIdx.x * ENT_PB;
  const int t = threadIdx.x;
  const int lane = t & 63, w = t >> 6;

  int myn[16], mye[16], pos[16];
  #pragma unroll
  for (int k=0;k<16;k++){
    int i = base + t + k*256;
    if (i < NNZ_){ myn[k]=nd[i]; mye[k]=ed[i]; }
    else { myn[k]=-1; mye[k]=-1; }
  }

  cnt[t] = 0;
  __syncthreads();
  #pragma unroll
  for (int k=0;k<16;k++)
    if (mye[k] >= 0) pos[k] = atomicAdd(&cnt[mye[k]>>5], 1);
  __syncthreads();
  {
    int v = cnt[t], s = v;
    #pragma unroll
    for (int d=1; d<64; d<<=1){ int u=__shfl_up(s,d); if (lane>=d) s+=u; }
    if (lane==63) wsum[w]=s;
    __syncthreads();
    int wb=0;
    for (int i=0;i<w;i++) wb+=wsum[i];
    off[t] = wb + s - v;
    __syncthreads();
  }
  #pragma unroll
  for (int k=0;k<16;k++)
    if (mye[k] >= 0)
      lbin[off[mye[k]>>5] + pos[k]] = ((unsigned)mye[k] << 15) | (unsigned)myn[k];
  if (t < NBKT && cnt[t] > 0) gbase[t] = atomicAdd(&gcnt_e[mod*NBKT + t], cnt[t]);
  __syncthreads();
  {
    int total = off[255];
    unsigned* dstreg = pe_part + (size_t)mod*NBKT*BCAP;
    for (int i=t; i<total; i+=256){
      unsigned pk = lbin[i];
      int b = pk >> 20;
      int gp = gbase[b] + (i - off[b]);
      if (gp < BCAP) dstreg[(size_t)b*BCAP + gp] = pk;
    }
  }
  __syncthreads();

  cnt[t] = 0;
  __syncthreads();
  #pragma unroll
  for (int k=0;k<16;k++)
    if (myn[k] >= 0) pos[k] = atomicAdd(&cnt[myn[k]>>7], 1);
  __syncthreads();
  {
    int v = cnt[t], s = v;
    #pragma unroll
    for (int d=1; d<64; d<<=1){ int u=__shfl_up(s,d); if (lane>=d) s+=u; }
    if (lane==63) wsum[w]=s;
    __syncthreads();
    int wb=0;
    for (int i=0;i<w;i++) wb+=wsum[i];
    off[t] = wb + s - v;
    __syncthreads();
  }
  #pragma unroll
  for (int k=0;k<16;k++)
    if (myn[k] >= 0)
      lbin[off[myn[k]>>7] + pos[k]] = ((unsigned)myn[k] << 13) | (unsigned)mye[k];
  if (t < NBKT && cnt[t] > 0) gbase[t] = atomicAdd(&gcnt_n[mod*NBKT + t], cnt[t]);
  __syncthreads();
  {
    int total = off[255];
    unsigned* dstreg = pn_part + (size_t)mod*NBKT*BCAP;
    for (int i=t; i<total; i+=256){
      unsigned pk = lbin[i];
      int b = pk >> 20;
      int gp = gbase[b] + (i - off[b]);
      if (gp < BCAP) dstreg[(size_t)b*BCAP + gp] = pk;
    }
  }
}

// ---------------- binB (merged e+n) ----------------
__global__ __launch_bounds__(256) void binB(const unsigned* __restrict__ pe_part,
    const unsigned* __restrict__ pn_part,
    const int* __restrict__ gcnt_e, const int* __restrict__ gcnt_n,
    int* __restrict__ cnt_all,
    unsigned short* __restrict__ e_slot, unsigned short* __restrict__ n_slot)
{
  __shared__ unsigned short ls[128*CAPN_];
  __shared__ int lc[128];
  const int y = blockIdx.y, b = blockIdx.x, t = threadIdx.x;
  if (y < 3){
    const int mod = y;
    if (t < 32) lc[t] = 0;
    __syncthreads();
    int cnt = gcnt_e[mod*NBKT + b];
    if (cnt > BCAP) cnt = BCAP;
    const unsigned* src = pe_part + ((size_t)mod*NBKT + b)*BCAP;
    for (int i=t; i<cnt; i+=256){
      unsigned pk = src[i];
      int el = (pk >> 15) - b*32;
      int n  = pk & 0x7FFF;
      int p = atomicAdd(&lc[el], 1);
      if (p < CAPE_) ls[el*CAPE_ + p] = (unsigned short)n;
    }
    __syncthreads();
    int rows = E_ - b*32; if (rows > 32) rows = 32;
    if (t < rows) cnt_all[mod*(E_+N_) + b*32 + t] = lc[t];
    const unsigned* lsu = (const unsigned*)ls;
    unsigned* dst = (unsigned*)(e_slot + ((size_t)mod*E_ + b*32)*CAPE_);
    int tot = rows*CAPE_/2;
    for (int i=t; i<tot; i+=256) dst[i] = lsu[i];
  } else {
    const int mod = y - 3;
    if (t < 128) lc[t] = 0;
    __syncthreads();
    int cnt = gcnt_n[mod*NBKT + b];
    if (cnt > BCAP) cnt = BCAP;
    const unsigned* src = pn_part + ((size_t)mod*NBKT + b)*BCAP;
    for (int i=t; i<cnt; i+=256){
      unsigned pk = src[i];
      int nl = (pk >> 13) - b*128;
      int e  = pk & 0x1FFF;
      int p = atomicAdd(&lc[nl], 1);
      if (p < CAPN_) ls[nl*CAPN_ + p] = (unsigned short)e;
    }
    __syncthreads();
    int rows = N_ - b*128; if (rows > 128) rows = 128;
    if (t < rows) cnt_all[mod*(E_+N_) + E_ + b*128 + t] = lc[t];
    const unsigned* lsu = (const unsigned*)ls;
    unsigned* dst = (unsigned*)(n_slot + ((size_t)mod*N_ + b*128)*CAPN_);
    int tot = rows*CAPN_/2;
    for (int i=t; i<tot; i+=256) dst[i] = lsu[i];
  }
}

// ---------------- wave-per-edge gather-mean (2 rows/load, 8-deep ILP = 16 rows in flight) ----------------
__global__ __launch_bounds__(256) void e_gather_w(const unsigned short* __restrict__ xb,
    const int* __restrict__ cnt_all, const unsigned short* __restrict__ e_slot,
    float* __restrict__ m_mean)
{
  int mod = blockIdx.y;
  int w = threadIdx.x >> 6, lane = threadIdx.x & 63;
  int rsel = lane >> 5, rlane = lane & 31;
  int e = blockIdx.x*4 + w;
  const unsigned short* x = xb + (size_t)mod*N_*D_;
  int cnt = cnt_all[mod*(E_+N_) + e];
  int c2 = (cnt < CAPE_) ? cnt : CAPE_;
  const unsigned short* slot = e_slot + ((size_t)mod*E_ + e)*CAPE_;
  float a0=0.f,a1=0.f,a2=0.f,a3=0.f;
  int j=0;
  for (; j+15 < c2; j += 16){
    uint2 uu[8];
    #pragma unroll
    for (int k=0;k<8;k++)
      uu[k] = *(const uint2*)(x + (size_t)slot[j + 2*k + rsel]*128 + rlane*4);
    #pragma unroll
    for (int k=0;k<8;k++){
      a0 += blo(uu[k].x); a1 += bhi(uu[k].x);
      a2 += blo(uu[k].y); a3 += bhi(uu[k].y);
    }
  }
  for (; j < c2; j += 2){
    int jr = j + rsel;
    if (jr < c2){
      uint2 u0 = *(const uint2*)(x + (size_t)slot[jr]*128 + rlane*4);
      a0 += blo(u0.x); a1 += bhi(u0.x);
      a2 += blo(u0.y); a3 += bhi(u0.y);
    }
  }
  // merge the two half-wave row groups (lane L and L+32 hold the same dims)
  a0 += __shfl_xor(a0, 32);
  a1 += __shfl_xor(a1, 32);
  a2 += __shfl_xor(a2, 32);
  a3 += __shfl_xor(a3, 32);
  if (rsel == 0){
    float inv = 1.f / fmaxf((float)cnt, 1.f);
    float4 o; o.x=a0*inv; o.y=a1*inv; o.z=a2*inv; o.w=a3*inv;
    *(float4*)(m_mean + ((size_t)mod*E_ + e)*128 + rlane*4) = o;
  }
}

// ---------------- batched theta GEMM ----------------
__global__ __launch_bounds__(256) void gemm_b(GemmB g, int M)
{
  const float* A = g.A[blockIdx.y];
  const float* W = g.W[blockIdx.y];
  unsigned short* Cout = g.C[blockIdx.y];
  __shared__ float As[64][33];
  __shared__ float Ws[32][128];
  const int t  = threadIdx.x;
  const int br = blockIdx.x * 64;
  const int r0 = (t >> 5) * 8;
  const int c0 = (t & 31) * 4;
  const int lr = t >> 2;
  const int lk = (t & 3) * 8;
  const int wk = t >> 5;

  float acc[8][4];
  #pragma unroll
  for (int i=0;i<8;i++){ acc[i][0]=0.f; acc[i][1]=0.f; acc[i][2]=0.f; acc[i][3]=0.f; }

  for (int kb=0; kb<128; kb+=32){
    float av[8];
    const int grow = br + lr;
    if (grow < M){
      const float* p = A + (size_t)grow*128 + kb + lk;
      float4 a = ((const float4*)p)[0], b = ((const float4*)p)[1];
      av[0]=a.x;av[1]=a.y;av[2]=a.z;av[3]=a.w;av[4]=b.x;av[5]=b.y;av[6]=b.z;av[7]=b.w;
    } else {
      #pragma unroll
      for (int j=0;j<8;j++) av[j]=0.f;
    }
    float4 wv4[4];
    #pragma unroll
    for (int kk=0;kk<4;kk++) wv4[kk] = *(const float4*)&W[(size_t)(kb + wk + kk*8)*128 + c0];

    __syncthreads();
    #pragma unroll
    for (int j=0;j<8;j++) As[lr][lk+j] = av[j];
    #pragma unroll
    for (int kk=0;kk<4;kk++) *(float4*)&Ws[wk + kk*8][c0] = wv4[kk];
    __syncthreads();

    #pragma unroll
    for (int k=0;k<32;k++){
      float4 wv = *(const float4*)&Ws[k][c0];
      #pragma unroll
      for (int i=0;i<8;i++){
        float a = As[r0+i][k];
        acc[i][0] = fmaf(a, wv.x, acc[i][0]);
        acc[i][1] = fmaf(a, wv.y, acc[i][1]);
        acc[i][2] = fmaf(a, wv.z, acc[i][2]);
        acc[i][3] = fmaf(a, wv.w, acc[i][3]);
      }
    }
  }

  #pragma unroll
  for (int i=0;i<8;i++){
    int gr = br + r0 + i;
    if (gr < M){
      ushort4 o;
      o.x=f2b(acc[i][0]); o.y=f2b(acc[i][1]); o.z=f2b(acc[i][2]); o.w=f2b(acc[i][3]);
      *(ushort4*)(Cout + (size_t)gr*128 + c0) = o;
    }
  }
}

// ---------------- wave-per-node gather-mean + bias -> bf16 related (2 rows/load) ----------------
__global__ __launch_bounds__(256) void n_gather_w(const unsigned short* __restrict__ m_buf,
    const int* __restrict__ cnt_all, const unsigned short* __restrict__ n_slot,
    Ptr3f biases, unsigned short* __restrict__ relbf)
{
  int mod = blockIdx.y;
  int w = threadIdx.x >> 6, lane = threadIdx.x & 63;
  int rsel = lane >> 5, rlane = lane & 31;
  int n = blockIdx.x*4 + w;
  const unsigned short* m = m_buf + (size_t)mod*E_*D_;
  int cnt = cnt_all[mod*(E_+N_) + E_ + n];
  int c2 = (cnt < CAPN_) ? cnt : CAPN_;
  const unsigned short* slot = n_slot + ((size_t)mod*N_ + n)*CAPN_;
  float a0=0.f,a1=0.f,a2=0.f,a3=0.f;
  int j=0;
  for (; j+15 < c2; j += 16){
    uint2 uu[8];
    #pragma unroll
    for (int k=0;k<8;k++)
      uu[k] = *(const uint2*)(m + (size_t)slot[j + 2*k + rsel]*128 + rlane*4);
    #pragma unroll
    for (int k=0;k<8;k++){
      a0 += blo(uu[k].x); a1 += bhi(uu[k].x);
      a2 += blo(uu[k].y); a3 += bhi(uu[k].y);
    }
  }
  for (; j < c2; j += 2){
    int jr = j + rsel;
    if (jr < c2){
      uint2 u0 = *(const uint2*)(m + (size_t)slot[jr]*128 + rlane*4);
      a0 += blo(u0.x); a1 += bhi(u0.x);
      a2 += blo(u0.y); a3 += bhi(u0.y);
    }
  }
  a0 += __shfl_xor(a0, 32);
  a1 += __shfl_xor(a1, 32);
  a2 += __shfl_xor(a2, 32);
  a3 += __shfl_xor(a3, 32);
  if (rsel == 0){
    float inv = 1.f / fmaxf((float)cnt, 1.f);
    const float* bs = biases.p[mod] + rlane*4;
    float v0 = a0*inv + bs[0];
    float v1 = a1*inv + bs[1];
    float v2 = a2*inv + bs[2];
    float v3 = a3*inv + bs[3];
    uint2 o; o.x = pk2(v0, v1); o.y = pk2(v2, v3);
    *(uint2*)(relbf + ((size_t)mod*N_ + n)*128 + rlane*4) = o;
  }
}

// ---------------- MFMA KV GEMM: bfB staged in LDS, 256 rows/block ----------------
__global__ __launch_bounds__(256) void gemm_kv_mfma(const unsigned short* __restrict__ relbf,
    const unsigned short* __restrict__ bfB, const float* __restrict__ bk,
    const float* __restrict__ bv, unsigned short* __restrict__ Kb,
    unsigned short* __restrict__ Vtg)
{
  __shared__ unsigned short Bs[32768];   // all of bfB, 64 KB
  const int t = threadIdx.x, w = t >> 6, L = t & 63;
  const int m = L & 15, quad = L >> 4, x = m;

  {
    const uint4* src = (const uint4*)bfB;
    uint4* dst = (uint4*)Bs;
    for (int i = t; i < 4096; i += 256) dst[i] = src[i];
  }
  __syncthreads();

  const int rowbase = blockIdx.x*256;
  for (int g = 0; g < 4; g++){
    const int j0 = rowbase + g*64 + w*16;

    bf16x8 a[4];
    {
      int row = j0 + m;
      int rowc = (row < NK_) ? row : (NK_-1);
      #pragma unroll
      for (int kb=0; kb<4; kb++)
        a[kb] = *(const bf16x8*)(relbf + (size_t)rowc*128 + kb*32 + quad*8);
    }

    f32x4 acc[16];
    #pragma unroll
    for (int tt=0; tt<16; tt++) acc[tt] = (f32x4){0.f,0.f,0.f,0.f};

    #pragma unroll
    for (int kb=0; kb<4; kb++){
      #pragma unroll
      for (int tt=0; tt<16; tt++){
        bf16x8 b = *(const bf16x8*)&Bs[(((tt*4 + kb)*64 + L) << 3)];
        acc[tt] = __builtin_amdgcn_mfma_f32_16x16x32_bf16(a[kb], b, acc[tt], 0, 0, 0);
      }
    }

    #pragma unroll
    for (int tt=0; tt<16; tt++){
      int h = tt & 7, kv = tt >> 3;
      float bias = (kv ? bv : bk)[h*16 + x];
      #pragma unroll
      for (int r=0; r<4; r++){
        int jr = j0 + quad*4 + r;
        if (jr < NK_){
          unsigned short val = f2b(acc[tt][r] + bias);
          if (kv == 0) Kb[(((size_t)h*NK_ + jr) << 4) + x] = val;
          else         Vtg[((size_t)(h*16 + x))*NK_ + jr] = val;
        }
      }
    }
  }
}

// ---------------- MFMA flash with in-block 4-wave merge ----------------
__global__ __launch_bounds__(256) void flash3(const unsigned short* __restrict__ Kb,
    const unsigned short* __restrict__ Vtg, const unsigned short* __restrict__ bfQ,
    float* __restrict__ part)
{
  __shared__ unsigned short P_lds[4][64][40];
  __shared__ float mbuf[4][64][18];
  const int c = blockIdx.x, h = blockIdx.y;
  const int t = threadIdx.x, w = t >> 6, L = t & 63;
  const int n = L & 15, quad = L >> 4;

  bf16x8 qb[4];
  #pragma unroll
  for (int qt=0; qt<4; qt++)
    qb[qt] = *(const bf16x8*)(bfQ + (((h*4 + qt)*64 + L) << 3));

  float Mc[4], Lc[4];
  f32x4 accq[4];
  #pragma unroll
  for (int qt=0; qt<4; qt++){ Mc[qt] = -INFINITY; Lc[qt] = 0.f; accq[qt] = (f32x4){0.f,0.f,0.f,0.f}; }

  const int base = c*2048 + w*512;
  unsigned* Pw = (unsigned*)&P_lds[w][0][0];

  for (int tile=0; tile<16; tile++){
    const int j0 = base + tile*32;
    const bool dead = (j0 >= NK_);

    bf16x8 a0 = (bf16x8){0,0,0,0,0,0,0,0};
    bf16x8 a1 = a0;
    if (quad < 2){
      int k0 = j0 + n;      if (k0 > NK_-1) k0 = NK_-1;
      int k1 = j0 + 16 + n; if (k1 > NK_-1) k1 = NK_-1;
      a0 = *(const bf16x8*)(Kb + (((size_t)h*NK_ + k0) << 4) + quad*8);
      a1 = *(const bf16x8*)(Kb + (((size_t)h*NK_ + k1) << 4) + quad*8);
    }
    f32x4 s0[4], s1[4];
    #pragma unroll
    for (int qt=0; qt<4; qt++){
      s0[qt] = __builtin_amdgcn_mfma_f32_16x16x32_bf16(a0, qb[qt], (f32x4){0.f,0.f,0.f,0.f}, 0,0,0);
      s1[qt] = __builtin_amdgcn_mfma_f32_16x16x32_bf16(a1, qb[qt], (f32x4){0.f,0.f,0.f,0.f}, 0,0,0);
    }

    #pragma unroll
    for (int qt=0; qt<4; qt++){
      float mt = s0[qt][0];
      mt = fmaxf(mt, s0[qt][1]); mt = fmaxf(mt, s0[qt][2]); mt = fmaxf(mt, s0[qt][3]);
      mt = fmaxf(mt, s1[qt][0]); mt = fmaxf(mt, s1[qt][1]);
      mt = fmaxf(mt, s1[qt][2]); mt = fmaxf(mt, s1[qt][3]);
      mt = fmaxf(mt, __shfl_xor(mt, 16));
      mt = fmaxf(mt, __shfl_xor(mt, 32));
      float Mn = fmaxf(Mc[qt], mt);
      float corr = __expf(Mc[qt] - Mn);
      Mc[qt] = Mn;
      float p0[4], p1[4];
      #pragma unroll
      for (int r=0;r<4;r++){
        p0[r] = __expf(s0[qt][r] - Mn);
        p1[r] = __expf(s1[qt][r] - Mn);
      }
      if (dead){
        #pragma unroll
        for (int r=0;r<4;r++){ p0[r]=0.f; p1[r]=0.f; }
      }
      float lt = p0[0]+p0[1]+p0[2]+p0[3]+p1[0]+p1[1]+p1[2]+p1[3];
      lt += __shfl_xor(lt, 16);
      lt += __shfl_xor(lt, 32);
      Lc[qt] = Lc[qt]*corr + lt;
      int rb = (qt*16 + n)*20;
      Pw[rb + quad*2]     = pk2(p0[0], p0[1]);
      Pw[rb + quad*2 + 1] = pk2(p0[2], p0[3]);
      Pw[rb + 8 + quad*2]     = pk2(p1[0], p1[1]);
      Pw[rb + 8 + quad*2 + 1] = pk2(p1[2], p1[3]);
      #pragma unroll
      for (int r=0;r<4;r++){
        float cr = __shfl(corr, quad*4 + r);
        accq[qt][r] *= cr;
      }
    }
    __syncthreads();

    bf16x8 bv_;
    {
      int va = j0 + quad*8; if (va > NK_-8) va = NK_-8;
      bv_ = *(const bf16x8*)(Vtg + ((size_t)(h*16 + n))*NK_ + va);
    }
    #pragma unroll
    for (int qt=0; qt<4; qt++){
      bf16x8 pa = *(const bf16x8*)&P_lds[w][qt*16 + n][quad*8];
      accq[qt] = __builtin_amdgcn_mfma_f32_16x16x32_bf16(pa, bv_, accq[qt], 0,0,0);
    }
    __syncthreads();
  }

  #pragma unroll
  for (int qt=0; qt<4; qt++){
    #pragma unroll
    for (int r=0; r<4; r++)
      mbuf[w][qt*16 + quad*4 + r][2 + n] = accq[qt][r];
    if (quad == 0){
      mbuf[w][qt*16 + n][0] = Mc[qt];
      mbuf[w][qt*16 + n][1] = Lc[qt];
    }
  }
  __syncthreads();
  if (t < C_){
    float M = mbuf[0][t][0], Lm = mbuf[0][t][1];
    float A[16];
    #pragma unroll
    for (int i=0;i<16;i++) A[i] = mbuf[0][t][2+i];
    #pragma unroll
    for (int ww=1; ww<4; ww++){
      float pm = mbuf[ww][t][0], pl = mbuf[ww][t][1];
      if (pl > 0.f){
        float mn = fmaxf(M, pm);
        float c1 = __expf(M - mn), c2 = __expf(pm - mn);
        Lm = Lm*c1 + pl*c2;
        #pragma unroll
        for (int i=0;i<16;i++) A[i] = A[i]*c1 + mbuf[ww][t][2+i]*c2;
        M = mn;
      }
    }
    float* pp = part + ((size_t)(h*NCH3 + c)*C_ + t)*18;
    pp[0] = M; pp[1] = Lm;
    #pragma unroll
    for (int i=0;i<16;i++) pp[2+i] = A[i];
  }
}

// ---------------- fused flash-reduce (two-pass, ILP) + O-projection + e1 row ----------------
__global__ __launch_bounds__(128) void reduce_oproj_e1(const float* __restrict__ part,
    const float* __restrict__ Wo, const float* __restrict__ bo,
    const float* __restrict__ a1, const float* __restrict__ b1,
    float* __restrict__ attentive, float* __restrict__ e1)
{
  __shared__ float row[128];
  __shared__ float orow[128];
  __shared__ float red[2];
  const int q = blockIdx.x, t = threadIdx.x;
  const int h = t >> 4, x = t & 15;
  const float* pbase = part + ((size_t)h*NCH3*C_ + q)*18;

  float M = -INFINITY;
  #pragma unroll 5
  for (int c=0; c<NCH3; c++){
    const float* p = pbase + (size_t)c*C_*18;
    float pm = p[0], pl = p[1];
    M = fmaxf(M, (pl > 0.f) ? pm : -INFINITY);
  }
  float l = 0.f, a = 0.f;
  #pragma unroll 5
  for (int c=0; c<NCH3; c++){
    const float* p = pbase + (size_t)c*C_*18;
    float pm = p[0], pl = p[1];
    float wgt = (pl > 0.f) ? __expf(pm - M) : 0.f;
    l = fmaf(pl, wgt, l);
    a = fmaf(p[2+x], wgt, a);
  }
  row[t] = a / l;
  __syncthreads();
  float s0=0.f,s1=0.f,s2=0.f,s3=0.f;
  for (int d=0; d<128; d+=4){
    s0 = fmaf(row[d],   Wo[(size_t) d   *128 + t], s0);
    s1 = fmaf(row[d+1], Wo[(size_t)(d+1)*128 + t], s1);
    s2 = fmaf(row[d+2], Wo[(size_t)(d+2)*128 + t], s2);
    s3 = fmaf(row[d+3], Wo[(size_t)(d+3)*128 + t], s3);
  }
  float o = s0+s1+s2+s3 + bo[t];
  attentive[(size_t)q*128 + t] = o;
  orow[t] = o;
  __syncthreads();
  float e0=0.f,e1s=0.f,e2s=0.f,e3s=0.f;
  for (int d=0; d<128; d+=4){
    e0 = fmaf(orow[d],   a1[(size_t) d   *128 + t], e0);
    e1s= fmaf(orow[d+1], a1[(size_t)(d+1)*128 + t], e1s);
    e2s= fmaf(orow[d+2], a1[(size_t)(d+2)*128 + t], e2s);
    e3s= fmaf(orow[d+3], a1[(size_t)(d+3)*128 + t], e3s);
  }
  float v = tanhf(e0+e1s+e2s+e3s) * b1[t];
  #pragma unroll
  for (int k=32; k>=1; k>>=1) v += __shfl_xor(v, k);
  if ((t & 63) == 0) red[t>>6] = v;
  __syncthreads();
  if (t == 0) e1[q] = red[0] + red[1];
}

// ---------------- tail_mid ----------------
__global__ __launch_bounds__(128) void tail_mid(const float* __restrict__ attentive,
    const float* __restrict__ ctx, const float* __restrict__ a2, const float* __restrict__ b2,
    const float* __restrict__ e1, const float* __restrict__ e2, float* __restrict__ user_repr)
{
  __shared__ float p[64];
  __shared__ float u[128];
  __shared__ float red[2];
  __shared__ float p2[64];
  const int t = threadIdx.x;

  if (t == 0){
    float mx=-INFINITY;
    for (int i=0;i<C_;i++) mx=fmaxf(mx,e1[i]);
    float ss=0.f;
    for (int i=0;i<C_;i++){ p[i]=__expf(e1[i]-mx); ss+=p[i]; }
    float inv=1.f/ss;
    for (int i=0;i<C_;i++) p[i]*=inv;
  }
  __syncthreads();
  {
    float s=0.f;
    for (int r=0;r<C_;r++) s = fmaf(p[r], attentive[(size_t)r*128 + t], s);
    u[t] = s;
  }
  __syncthreads();
  {
    float s0=0.f,s1=0.f,s2=0.f,s3=0.f;
    for (int d=0; d<128; d+=4){
      s0 = fmaf(u[d],   a2[(size_t) d   *128 + t], s0);
      s1 = fmaf(u[d+1], a2[(size_t)(d+1)*128 + t], s1);
      s2 = fmaf(u[d+2], a2[(size_t)(d+2)*128 + t], s2);
      s3 = fmaf(u[d+3], a2[(size_t)(d+3)*128 + t], s3);
    }
    float v = tanhf(s0+s1+s2+s3) * b2[t];
    #pragma unroll
    for (int k=32; k>=1; k>>=1) v += __shfl_xor(v, k);
    if ((t & 63) == 0) red[t>>6] = v;
  }
  __syncthreads();
  if (t == 0){
    float elast = red[0] + red[1];
    float mx=elast;
    for (int i=0;i<C_;i++) mx=fmaxf(mx,e2[i]);
    float ss=0.f;
    for (int i=0;i<C_;i++){ p2[i]=__expf(e2[i]-mx); ss+=p2[i]; }
    float pl = __expf(elast-mx); ss += pl;
    float inv=1.f/ss;
    for (int i=0;i<C_;i++) p2[i]*=inv;
    p2[C_] = pl*inv;
  }
  __syncthreads();
  {
    float s=0.f;
    for (int r=0;r<C_;r++) s = fmaf(p2[r], ctx[(size_t)r*128 + t], s);
    s = fmaf(p2[C_], u[t], s);
    user_repr[t] = s;
  }
}

__global__ __launch_bounds__(256) void scores_k(const float* __restrict__ ur,
    const float* __restrict__ recW, const float* __restrict__ recb, float* __restrict__ out)
{
  __shared__ float u[128];
  int t = threadIdx.x;
  if (t < 128) u[t] = ur[t];
  __syncthreads();
  int j = blockIdx.x*256 + t;
  if (j < NENT_){
    float s0=0.f,s1=0.f,s2=0.f,s3=0.f;
    for (int d=0; d<128; d+=4){
      s0 = fmaf(u[d],   recW[(size_t) d   *NENT_ + j], s0);
      s1 = fmaf(u[d+1], recW[(size_t)(d+1)*NENT_ + j], s1);
      s2 = fmaf(u[d+2], recW[(size_t)(d+2)*NENT_ + j], s2);
      s3 = fmaf(u[d+3], recW[(size_t)(d+3)*NENT_ + j], s3);
    }
    out[j] = s0+s1+s2+s3 + recb[j];
  }
}

// ---------------- launcher ----------------
extern "C" void kernel_launch(void* const* d_in, const int* in_sizes, int n_in,
                              void* d_out, int out_size, void* d_ws, size_t ws_size,
                              hipStream_t stream)
{
  auto f32 = [&](int i){ return (const float*)d_in[i]; };
  Ptr3i nodes = {{(const int*)d_in[24], (const int*)d_in[26], (const int*)d_in[28]}};
  Ptr3i edges = {{(const int*)d_in[25], (const int*)d_in[27], (const int*)d_in[29]}};

  // ---- workspace layout (~75 MB) ----
  char* base = (char*)d_ws;
  int*   cnt_all = (int*)base;
  int*   gcnt_e  = (int*)(base + 300064);
  int*   gcnt_n  = gcnt_e + NBKT*3;
  unsigned short* n_slot = (unsigned short*)(base + 300064 + 4096);
  float* m_mean  = (float*)((char*)n_slot + 7680000);
  unsigned short* m_buf = (unsigned short*)((char*)m_mean + 7680000);
  unsigned short* relbf = (unsigned short*)((char*)m_buf + 3840000);
  unsigned short* bfB   = (unsigned short*)((char*)relbf + 15360000);
  unsigned short* bfQ   = (unsigned short*)((char*)bfB + 65536);
  float* attentive = (float*)((char*)bfQ + 32768);
  float* user_repr = (float*)((char*)attentive + 25600);
  float* e1buf     = user_repr + 128;
  float* e2buf     = e1buf + 64;
  float* fpart = (float*)relbf;   // overlays relbf (dead after gemm_kv_mfma)
  char* U = (char*)(e2buf + 64);
  unsigned* pe_part = (unsigned*)U;
  unsigned* pn_part = pe_part + (size_t)3*NBKT*BCAP;
  unsigned short* e_slot = (unsigned short*)(pn_part + (size_t)3*NBKT*BCAP);
  unsigned short* xb     = e_slot + (size_t)3*E_*CAPE_;
  unsigned short* Kb  = (unsigned short*)U;
  unsigned short* Vtg = Kb + (size_t)H_*NK_*16;

  // ---- prep (+ctx-tail e2 rows) ----
  Ptr3f xs = {{f32(0), f32(1), f32(2)}};
  prep<<<PB_TOT, 256, 0, stream>>>(xs, xb, f32(12), f32(14), bfB, gcnt_e, gcnt_n,
                                   f32(3), f32(10), f32(11), bfQ, f32(20), f32(21), e2buf);

  // ---- binned CSR build ----
  binA<<<dim3(ABLK, 3), 256, 0, stream>>>(nodes, edges, pe_part, pn_part, gcnt_e, gcnt_n);
  binB<<<dim3(NBKT, 6), 256, 0, stream>>>(pe_part, pn_part, gcnt_e, gcnt_n, cnt_all,
                                          e_slot, n_slot);

  // ---- hyperconv gathers + theta GEMM ----
  e_gather_w<<<dim3(E_/4, 3), 256, 0, stream>>>(xb, cnt_all, e_slot, m_mean);
  GemmB g;
  for (int mod=0; mod<3; mod++){
    g.A[mod] = m_mean + (size_t)mod*E_*D_;
    g.W[mod] = f32(4 + 2*mod);
    g.C[mod] = m_buf + (size_t)mod*E_*D_;
  }
  gemm_b<<<dim3((E_+63)/64, 3), 256, 0, stream>>>(g, E_);
  Ptr3f biases = {{f32(5), f32(7), f32(9)}};
  n_gather_w<<<dim3(N_/4, 3), 256, 0, stream>>>(m_buf, cnt_all, n_slot, biases, relbf);

  // ---- MHA ----
  gemm_kv_mfma<<<KVBLK, 256, 0, stream>>>(relbf, bfB, f32(13), f32(15), Kb, Vtg);
  flash3<<<dim3(NCH3, H_), 256, 0, stream>>>(Kb, Vtg, bfQ, fpart);
  reduce_oproj_e1<<<C_, 128, 0, stream>>>(fpart, f32(16), f32(17), f32(18), f32(19),
                                          attentive, e1buf);

  // ---- tail ----
  tail_mid<<<1, 128, 0, stream>>>(attentive, f32(3), f32(20), f32(21), e1buf, e2buf, user_repr);
  scores_k<<<(NENT_+255)/256, 256, 0, stream>>>(user_repr, f32(22), f32(23), (float*)d_out);
}